// Round 4
// baseline (909.056 us; speedup 1.0000x reference)
//
#include <hip/hip_runtime.h>

#define NN 50000
#define NE 500000
#define DD 128
#define KK 25000

__device__ inline unsigned short f2bf(float x) {
  unsigned u = __float_as_uint(x);
  unsigned r = (u + 0x7FFFu + ((u >> 16) & 1u)) >> 16;
  return (unsigned short)r;
}
__device__ inline float bf2f(unsigned short b) {
  return __uint_as_float(((unsigned)b) << 16);
}

// ---------------- zero init ----------------
__global__ void k_zero(float* zf, int nf, int* zi, int ni) {
  int i = blockIdx.x * blockDim.x + threadIdx.x;
  int stride = gridDim.x * blockDim.x;
  for (int k = i; k < nf; k += stride) zf[k] = 0.0f;
  for (int k = i; k < ni; k += stride) zi[k] = 0;
}

// ---------------- small composed matrices (f32), 68 blocks ----------------
// blocks 0..63: mat = b>>4, rows 2*(b&15).. ; block 64..67: vecs[which]
__global__ void k_smallmats(const float* __restrict__ Wb, const float* __restrict__ wkw,
                            const float* __restrict__ wvw, float* Ck0, float* Ck1,
                            float* Dk0, float* Dk1, float* vecs) {
  int b = blockIdx.x, tid = threadIdx.x;
  if (b < 64) {
    int mat = b >> 4;               // 0..3 : Ck0, Ck1, Dk0, Dk1
    int basis = mat & 1;
    int rowoff = (mat >> 1) * DD;
    float* outp = (mat == 0) ? Ck0 : ((mat == 1) ? Ck1 : ((mat == 2) ? Dk0 : Dk1));
    int i = (b & 15) * 2 + (tid >> 7);   // row 0..127
    int t = tid & 127;                    // col
    const float* wrow = Wb + (size_t)(basis * 2 * DD + rowoff + i) * DD;
    float s = 0.0f;
    for (int m = 0; m < DD; m++) s += wrow[m] * wkw[m * DD + t];
    outp[i * DD + t] = s;
  } else if (b < 68) {
    int which = b - 64;
    int basis = which & 1, rowoff = (which >> 1) * DD;
    if (tid < DD) {
      const float* wrow = Wb + (size_t)(basis * 2 * DD + rowoff + tid) * DD;
      float s = 0.0f;
      for (int m = 0; m < DD; m++) s += wrow[m] * wvw[m];
      vecs[which * DD + tid] = s;
    }
  }
}

// ---------------- fused node-level matvec ----------------
// MODE 0: outq[n][:] = h[n]@M0 + bias
// MODE 1: PK01[n][k][2] = bf16(h[n]@M0)[k], bf16(h[n]@M1)[k]
template <int MODE>
__global__ void __launch_bounds__(256) k_matnode2(
    const float* __restrict__ h, const float* __restrict__ M0,
    const float* __restrict__ M1, const float* __restrict__ bias,
    float* __restrict__ outq, unsigned short* __restrict__ outpk) {
  __shared__ float hs[32 * DD];
  int tid = threadIdx.x;
  int n0 = blockIdx.x * 32;
  for (int idx = tid; idx < 32 * DD; idx += 256) {
    int n = n0 + (idx >> 7);
    hs[idx] = (n < NN) ? h[(size_t)n * DD + (idx & 127)] : 0.0f;
  }
  __syncthreads();
  int col = tid & 127, half = tid >> 7;
  float acc0[16], acc1[16];
#pragma unroll
  for (int j = 0; j < 16; j++) { acc0[j] = 0.0f; acc1[j] = 0.0f; }
  for (int k4 = 0; k4 < DD / 4; k4++) {
    float a0 = M0[(4 * k4 + 0) * DD + col];
    float a1 = M0[(4 * k4 + 1) * DD + col];
    float a2 = M0[(4 * k4 + 2) * DD + col];
    float a3 = M0[(4 * k4 + 3) * DD + col];
    float b0 = 0.f, b1 = 0.f, b2 = 0.f, b3 = 0.f;
    if (MODE != 0) {
      b0 = M1[(4 * k4 + 0) * DD + col];
      b1 = M1[(4 * k4 + 1) * DD + col];
      b2 = M1[(4 * k4 + 2) * DD + col];
      b3 = M1[(4 * k4 + 3) * DD + col];
    }
#pragma unroll
    for (int j = 0; j < 16; j++) {
      const float4 hv = *(const float4*)&hs[(half * 16 + j) * DD + 4 * k4];
      acc0[j] += hv.x * a0 + hv.y * a1 + hv.z * a2 + hv.w * a3;
      if (MODE != 0) acc1[j] += hv.x * b0 + hv.y * b1 + hv.z * b2 + hv.w * b3;
    }
  }
  if (MODE == 0) {
    for (int j = 0; j < 16; j++) {
      int n = n0 + half * 16 + j;
      if (n < NN) outq[(size_t)n * DD + col] = acc0[j] + bias[col];
    }
  } else {
    for (int j = 0; j < 16; j++) {
      int n = n0 + half * 16 + j;
      if (n < NN) {
        ushort2 st;
        st.x = f2bf(acc0[j]);
        st.y = f2bf(acc1[j]);
        *(ushort2*)&outpk[(size_t)n * 256 + 2 * col] = st;
      }
    }
  }
}

// ---------------- t0/t1: t_b[n] = (h[n]@Dk_b)·q[n], wave-local reduce ----------------
__global__ void __launch_bounds__(256) k_matdot(
    const float* __restrict__ h, const float* __restrict__ M0,
    const float* __restrict__ M1, const float* __restrict__ q_in,
    float* __restrict__ outt0, float* __restrict__ outt1) {
  __shared__ float hs[32 * DD];
  __shared__ float red2[4][16][2];
  int tid = threadIdx.x;
  int n0 = blockIdx.x * 32;
  for (int idx = tid; idx < 32 * DD; idx += 256) {
    int n = n0 + (idx >> 7);
    hs[idx] = (n < NN) ? h[(size_t)n * DD + (idx & 127)] : 0.0f;
  }
  __syncthreads();
  int col = tid & 127, half = tid >> 7;
  int lane = tid & 63, wid = tid >> 6;
  float acc0[16], acc1[16];
#pragma unroll
  for (int j = 0; j < 16; j++) { acc0[j] = 0.0f; acc1[j] = 0.0f; }
  for (int k4 = 0; k4 < DD / 4; k4++) {
    float a0 = M0[(4 * k4 + 0) * DD + col];
    float a1 = M0[(4 * k4 + 1) * DD + col];
    float a2 = M0[(4 * k4 + 2) * DD + col];
    float a3 = M0[(4 * k4 + 3) * DD + col];
    float b0 = M1[(4 * k4 + 0) * DD + col];
    float b1 = M1[(4 * k4 + 1) * DD + col];
    float b2 = M1[(4 * k4 + 2) * DD + col];
    float b3 = M1[(4 * k4 + 3) * DD + col];
#pragma unroll
    for (int j = 0; j < 16; j++) {
      const float4 hv = *(const float4*)&hs[(half * 16 + j) * DD + 4 * k4];
      acc0[j] += hv.x * a0 + hv.y * a1 + hv.z * a2 + hv.w * a3;
      acc1[j] += hv.x * b0 + hv.y * b1 + hv.z * b2 + hv.w * b3;
    }
  }
#pragma unroll
  for (int j = 0; j < 16; j++) {
    int n = n0 + half * 16 + j;
    float qv = (n < NN) ? q_in[(size_t)n * DD + col] : 0.0f;
    float v0 = acc0[j] * qv, v1 = acc1[j] * qv;
    for (int off = 32; off; off >>= 1) {
      v0 += __shfl_xor(v0, off);
      v1 += __shfl_xor(v1, off);
    }
    if (lane == 0) { red2[wid][j][0] = v0; red2[wid][j][1] = v1; }
  }
  __syncthreads();
  if (tid < 32) {
    int j = tid & 15, g = tid >> 4;   // g=0: nodes 0-15 (waves 0,1); g=1: nodes 16-31 (waves 2,3)
    int n = n0 + g * 16 + j;
    if (n < NN) {
      outt0[n] = red2[g * 2][j][0] + red2[g * 2 + 1][j][0];
      outt1[n] = red2[g * 2][j][1] + red2[g * 2 + 1][j][1];
    }
  }
}

// ---------------- per-node scalars (+ bf16 pack of q) ----------------
__global__ void k_nodescalars(const float* h, const float* q, const float* vecs,
                              const float* wkb, const float* coef, const float* wvb,
                              float* av0, float* av1, float* bv0, float* bv1,
                              float* u, float* selfy, unsigned short* qe) {
  int wid = threadIdx.x >> 6, lane = threadIdx.x & 63;
  int n = blockIdx.x * 4 + wid;
  if (n >= NN) return;
  const float* avv0 = vecs;
  const float* avv1 = vecs + DD;
  const float* bvv0 = vecs + 2 * DD;
  const float* bvv1 = vecs + 3 * DD;
  float h0 = h[(size_t)n * DD + lane], h1 = h[(size_t)n * DD + 64 + lane];
  float q0 = q[(size_t)n * DD + lane], q1 = q[(size_t)n * DD + 64 + lane];
  qe[(size_t)n * DD + lane] = f2bf(q0);
  qe[(size_t)n * DD + 64 + lane] = f2bf(q1);
  float a0 = h0 * avv0[lane] + h1 * avv0[64 + lane];
  float a1 = h0 * avv1[lane] + h1 * avv1[64 + lane];
  float b0 = h0 * bvv0[lane] + h1 * bvv0[64 + lane];
  float b1 = h0 * bvv1[lane] + h1 * bvv1[64 + lane];
  float uu = q0 * wkb[lane] + q1 * wkb[64 + lane];
  for (int off = 32; off; off >>= 1) {
    a0 += __shfl_xor(a0, off); a1 += __shfl_xor(a1, off);
    b0 += __shfl_xor(b0, off); b1 += __shfl_xor(b1, off);
    uu += __shfl_xor(uu, off);
  }
  if (lane == 0) {
    av0[n] = a0; av1[n] = a1; bv0[n] = b0; bv1[n] = b1; u[n] = uu;
    float c40 = coef[4 * 2 + 0], c41 = coef[4 * 2 + 1];
    selfy[n] = c40 * (a0 + b0) + c41 * (a1 + b1) + wvb[0];
  }
}

// ---------------- edge kernel: bf16 gathers, f32 accumulate ----------------
__global__ void __launch_bounds__(256) k_edges(
    const int* src, const int* dst, const int* et, const float* coef,
    const float* wvb, const unsigned short* __restrict__ PK,
    const unsigned short* __restrict__ QE, const float* t0, const float* t1,
    const float* u, const float* av0, const float* av1, const float* bv0,
    const float* bv1, float* wvin, float* zin, float* wvout, float* zout) {
  int wid = threadIdx.x >> 6, lane = threadIdx.x & 63;
  long e = (long)blockIdx.x * 4 + wid;
  if (e >= NE) return;
  int s = src[e], d = dst[e], t = et[e];
  float c0 = coef[t * 2], c1 = coef[t * 2 + 1];
  ushort4 pks = *(const ushort4*)&PK[(size_t)s * 256 + 4 * lane];
  ushort4 pkd = *(const ushort4*)&PK[(size_t)d * 256 + 4 * lane];
  ushort2 qse = *(const ushort2*)&QE[(size_t)s * DD + 2 * lane];
  ushort2 qde = *(const ushort2*)&QE[(size_t)d * DD + 2 * lane];
  float df = (c0 * bf2f(pks.x) + c1 * bf2f(pks.y)) * bf2f(qde.x) +
             (c0 * bf2f(pks.z) + c1 * bf2f(pks.w)) * bf2f(qde.y);
  float dr = (c0 * bf2f(pkd.x) + c1 * bf2f(pkd.y)) * bf2f(qse.x) +
             (c0 * bf2f(pkd.z) + c1 * bf2f(pkd.w)) * bf2f(qse.y);
  for (int off = 32; off; off >>= 1) {
    df += __shfl_xor(df, off);
    dr += __shfl_xor(dr, off);
  }
  if (lane == 0) {
    const float scale = 11.3137084989847604f;  // sqrt(128)
    float wvbd = wvb[0];
    float sf = (df + c0 * t0[d] + c1 * t1[d] + u[d]) / scale;
    sf = fminf(fmaxf(sf, -10.0f), 10.0f);
    float ef = expf(sf);
    float nvf = c0 * (av0[s] + bv0[d]) + c1 * (av1[s] + bv1[d]) + wvbd;
    atomicAdd(&wvin[d], ef * nvf);
    atomicAdd(&zin[d], ef);
    float sr = (dr + c0 * t0[s] + c1 * t1[s] + u[s]) / scale;
    sr = fminf(fmaxf(sr, -10.0f), 10.0f);
    float er = expf(sr);
    float nvr = c0 * (av0[d] + bv0[s]) + c1 * (av1[d] + bv1[s]) + wvbd;
    atomicAdd(&wvout[s], er * nvr);
    atomicAdd(&zout[s], er);
  }
}

// ---------------- y + monotonic u32 key ----------------
__device__ inline unsigned fkey(float f) {
  unsigned b = __float_as_uint(f);
  return (b & 0x80000000u) ? ~b : (b | 0x80000000u);
}

__global__ void k_y(const float* wvin, const float* zin, const float* wvout,
                    const float* zout, const float* selfy, float* y, unsigned* ykey) {
  int n = blockIdx.x * blockDim.x + threadIdx.x;
  if (n < NN) {
    float v = wvin[n] / (zin[n] + 1e-6f) + wvout[n] / (zout[n] + 1e-6f) + selfy[n];
    y[n] = v;
    ykey[n] = fkey(v);
  }
}

// ---------------- exact descending rank via u32 keys ----------------
// rank[i] = #{j : key_j > key_i  or (key_j == key_i and j < i)}
#define RIB 8
#define RITILE 2048  // 256 threads * 8
#define RJB 42
#define RJCH 1200    // 42 * 1200 = 50400 >= NN
__global__ void __launch_bounds__(256) k_rank2(const unsigned* __restrict__ key,
                                               int* __restrict__ rank) {
  __shared__ alignas(16) unsigned ks[RJCH + 4];
  int ilo = blockIdx.x * RITILE;
  int jlo = blockIdx.y * RJCH;
  for (int jj = threadIdx.x; jj < RJCH; jj += 256) {
    int j = jlo + jj;
    ks[jj] = (j < NN) ? key[j] : 0u;  // key 0 < any real key -> never counted
  }
  if (threadIdx.x < 4) ks[RJCH + threadIdx.x] = 0u;
  __syncthreads();
  int i0 = ilo + threadIdx.x * RIB;
  unsigned ki[RIB];
  int cnt[RIB];
#pragma unroll
  for (int r = 0; r < RIB; r++) {
    int i = i0 + r;
    ki[r] = (i < NN) ? key[i] : 0xFFFFFFFFu;
    cnt[r] = 0;
  }
  if (jlo + RJCH <= ilo) {
    // all j < i : count key_j >= key_i
    uint4 a = *(const uint4*)&ks[0];
    for (int jj = 0; jj < RJCH; jj += 4) {
      uint4 b = *(const uint4*)&ks[jj + 4];
#pragma unroll
      for (int r = 0; r < RIB; r++) {
        cnt[r] += (int)(a.x >= ki[r]) + (int)(a.y >= ki[r]) +
                  (int)(a.z >= ki[r]) + (int)(a.w >= ki[r]);
      }
      a = b;
    }
  } else if (jlo >= ilo + RITILE) {
    // all j > i : count key_j > key_i
    uint4 a = *(const uint4*)&ks[0];
    for (int jj = 0; jj < RJCH; jj += 4) {
      uint4 b = *(const uint4*)&ks[jj + 4];
#pragma unroll
      for (int r = 0; r < RIB; r++) {
        cnt[r] += (int)(a.x > ki[r]) + (int)(a.y > ki[r]) +
                  (int)(a.z > ki[r]) + (int)(a.w > ki[r]);
      }
      a = b;
    }
  } else {
    for (int jj = 0; jj < RJCH; jj++) {
      unsigned kj = ks[jj];
      int j = jlo + jj;
#pragma unroll
      for (int r = 0; r < RIB; r++) {
        int i = i0 + r;
        cnt[r] += (kj > ki[r] || (kj == ki[r] && j < i)) ? 1 : 0;
      }
    }
  }
#pragma unroll
  for (int r = 0; r < RIB; r++) {
    int i = i0 + r;
    if (i < NN) atomicAdd(&rank[i], cnt[r]);
  }
}

// ---------------- selection scatter ----------------
__global__ void k_bcnt(const int* rank, int* bcnt) {
  __shared__ int sh[256];
  int i = blockIdx.x * 256 + threadIdx.x;
  int f = (i < NN && rank[i] < KK) ? 1 : 0;
  sh[threadIdx.x] = f;
  __syncthreads();
  for (int off = 128; off; off >>= 1) {
    if (threadIdx.x < off) sh[threadIdx.x] += sh[threadIdx.x + off];
    __syncthreads();
  }
  if (threadIdx.x == 0) bcnt[blockIdx.x] = sh[0];
}

__global__ void k_scan(int* bcnt, int nb) {
  __shared__ int sh[256];
  int t = threadIdx.x;
  int v = (t < nb) ? bcnt[t] : 0;
  sh[t] = v;
  __syncthreads();
  for (int off = 1; off < 256; off <<= 1) {
    int u2 = (t >= off) ? sh[t - off] : 0;
    __syncthreads();
    sh[t] += u2;
    __syncthreads();
  }
  if (t < nb) bcnt[t] = sh[t] - v;  // exclusive
}

__global__ void k_scatter(const int* rank, const int* bcnt, const float* y,
                          float* out_ids, int* selp, float* sig) {
  __shared__ int sh[256];
  int i = blockIdx.x * 256 + threadIdx.x;
  int f = (i < NN && rank[i] < KK) ? 1 : 0;
  sh[threadIdx.x] = f;
  __syncthreads();
  for (int off = 1; off < 256; off <<= 1) {
    int v = (threadIdx.x >= off) ? sh[threadIdx.x - off] : 0;
    __syncthreads();
    sh[threadIdx.x] += v;
    __syncthreads();
  }
  if (f) {
    int slot = bcnt[blockIdx.x] + sh[threadIdx.x] - 1;
    out_ids[slot] = (float)i;
    int p = rank[i];  // position in descending-y list = sel index (faithful quirk)
    selp[slot] = p;
    sig[slot] = 1.0f / (1.0f + expf(-y[p]));
  }
}

__global__ void k_outh(const float* h, const int* selp, const float* sig, float* out) {
  long idx = (long)blockIdx.x * 256 + threadIdx.x;
  if (idx >= (long)KK * DD) return;
  int slot = (int)(idx >> 7), c = (int)(idx & 127);
  int p = selp[slot];
  out[KK + idx] = h[(size_t)p * DD + c] * sig[slot];
}

extern "C" void kernel_launch(void* const* d_in, const int* in_sizes, int n_in,
                              void* d_out, int out_size, void* d_ws, size_t ws_size,
                              hipStream_t stream) {
  const float* h = (const float*)d_in[0];
  const int* src = (const int*)d_in[1];
  const int* dst = (const int*)d_in[2];
  const int* etype = (const int*)d_in[3];
  const float* Wb = (const float*)d_in[4];
  const float* coef = (const float*)d_in[5];
  const float* wqw = (const float*)d_in[6];
  const float* wqb = (const float*)d_in[7];
  const float* wkw = (const float*)d_in[8];
  const float* wkb = (const float*)d_in[9];
  const float* wvw = (const float*)d_in[10];
  const float* wvb = (const float*)d_in[11];
  float* out = (float*)d_out;

  float* W = (float*)d_ws;
  size_t o = 0;
  float* q = W + o;    o += (size_t)NN * DD;
  unsigned short* PK01 = (unsigned short*)(W + o); o += (size_t)NN * DD;  // bf16 [n][128][2]
  unsigned short* qe = (unsigned short*)(W + o);   o += (size_t)NN * DD / 2;  // bf16 [n][128]
  float* Ck0 = W + o;  o += DD * DD;
  float* Ck1 = W + o;  o += DD * DD;
  float* Dk0 = W + o;  o += DD * DD;
  float* Dk1 = W + o;  o += DD * DD;
  float* vecs = W + o; o += 4 * DD;
  float* t0 = W + o;   o += NN;
  float* t1 = W + o;   o += NN;
  float* av0 = W + o;  o += NN;
  float* av1 = W + o;  o += NN;
  float* bv0 = W + o;  o += NN;
  float* bv1 = W + o;  o += NN;
  float* u = W + o;    o += NN;
  float* selfy = W + o; o += NN;
  float* wvin = W + o;  o += NN;  // zero region start (4*NN contiguous)
  float* zin = W + o;   o += NN;
  float* wvout = W + o; o += NN;
  float* zout = W + o;  o += NN;
  float* y = W + o;     o += NN;
  unsigned* ykey = (unsigned*)(W + o); o += NN;
  float* sig = W + o;   o += KK;
  int* ibase = (int*)(W + o);
  int* rank = ibase;
  int* bcnt = ibase + NN;
  int* selp = ibase + NN + 256;

  int nb = (NN + 255) / 256;  // 196
  int gx = (NN + 31) / 32;    // 1563

  k_zero<<<256, 256, 0, stream>>>(wvin, 4 * NN, rank, NN);
  k_smallmats<<<68, 256, 0, stream>>>(Wb, wkw, wvw, Ck0, Ck1, Dk0, Dk1, vecs);
  k_matnode2<0><<<gx, 256, 0, stream>>>(h, wqw, nullptr, wqb, q, nullptr);
  k_matnode2<1><<<gx, 256, 0, stream>>>(h, Ck0, Ck1, nullptr, nullptr, PK01);
  k_matdot<<<gx, 256, 0, stream>>>(h, Dk0, Dk1, q, t0, t1);
  k_nodescalars<<<(NN + 3) / 4, 256, 0, stream>>>(h, q, vecs, wkb, coef, wvb, av0, av1,
                                                  bv0, bv1, u, selfy, qe);
  k_edges<<<NE / 4, 256, 0, stream>>>(src, dst, etype, coef, wvb, PK01, qe, t0, t1, u,
                                      av0, av1, bv0, bv1, wvin, zin, wvout, zout);
  k_y<<<nb, 256, 0, stream>>>(wvin, zin, wvout, zout, selfy, y, ykey);
  k_rank2<<<dim3((NN + RITILE - 1) / RITILE, RJB), 256, 0, stream>>>(ykey, rank);
  k_bcnt<<<nb, 256, 0, stream>>>(rank, bcnt);
  k_scan<<<1, 256, 0, stream>>>(bcnt, nb);
  k_scatter<<<nb, 256, 0, stream>>>(rank, bcnt, y, out, selp, sig);
  k_outh<<<(KK * DD) / 256, 256, 0, stream>>>(h, selp, sig, out);
}

// Round 5
// 683.249 us; speedup vs baseline: 1.3305x; 1.3305x over previous
//
#include <hip/hip_runtime.h>

#define NN 50000
#define NE 500000
#define DD 128
#define KK 25000
#define NBIN 16384

typedef unsigned short u16;
typedef __attribute__((ext_vector_type(8))) unsigned short u16x8;

__device__ inline u16 f2bf(float x) {
  unsigned u = __float_as_uint(x);
  unsigned r = (u + 0x7FFFu + ((u >> 16) & 1u)) >> 16;
  return (u16)r;
}
__device__ inline float bf2f(u16 b) {
  return __uint_as_float(((unsigned)b) << 16);
}

// ---------------- zero init ----------------
__global__ void k_zero(float* zf, int nf, int* zi, int ni) {
  int i = blockIdx.x * blockDim.x + threadIdx.x;
  int stride = gridDim.x * blockDim.x;
  for (int k = i; k < nf; k += stride) zf[k] = 0.0f;
  for (int k = i; k < ni; k += stride) zi[k] = 0;
}

// ---------------- small composed matrices (f32), 68 blocks ----------------
__global__ void k_smallmats(const float* __restrict__ Wb, const float* __restrict__ wkw,
                            const float* __restrict__ wvw, float* Ck0, float* Ck1,
                            float* Dk0, float* Dk1, float* vecs) {
  int b = blockIdx.x, tid = threadIdx.x;
  if (b < 64) {
    int mat = b >> 4;
    int basis = mat & 1;
    int rowoff = (mat >> 1) * DD;
    float* outp = (mat == 0) ? Ck0 : ((mat == 1) ? Ck1 : ((mat == 2) ? Dk0 : Dk1));
    int i = (b & 15) * 2 + (tid >> 7);
    int t = tid & 127;
    const float* wrow = Wb + (size_t)(basis * 2 * DD + rowoff + i) * DD;
    float s = 0.0f;
    for (int m = 0; m < DD; m++) s += wrow[m] * wkw[m * DD + t];
    outp[i * DD + t] = s;
  } else if (b < 68) {
    int which = b - 64;
    int basis = which & 1, rowoff = (which >> 1) * DD;
    if (tid < DD) {
      const float* wrow = Wb + (size_t)(basis * 2 * DD + rowoff + tid) * DD;
      float s = 0.0f;
      for (int m = 0; m < DD; m++) s += wrow[m] * wvw[m];
      vecs[which * DD + tid] = s;
    }
  }
}

// ---------------- q pass: outq[n][:] = h[n]@M0 + bias ----------------
__global__ void __launch_bounds__(256) k_matq(
    const float* __restrict__ h, const float* __restrict__ M0,
    const float* __restrict__ bias, float* __restrict__ outq) {
  __shared__ float hs[32 * DD];
  int tid = threadIdx.x;
  int n0 = blockIdx.x * 32;
  for (int idx = tid; idx < 32 * DD; idx += 256) {
    int n = n0 + (idx >> 7);
    hs[idx] = (n < NN) ? h[(size_t)n * DD + (idx & 127)] : 0.0f;
  }
  __syncthreads();
  int col = tid & 127, half = tid >> 7;
  float acc0[16];
#pragma unroll
  for (int j = 0; j < 16; j++) acc0[j] = 0.0f;
  for (int k4 = 0; k4 < DD / 4; k4++) {
    float a0 = M0[(4 * k4 + 0) * DD + col];
    float a1 = M0[(4 * k4 + 1) * DD + col];
    float a2 = M0[(4 * k4 + 2) * DD + col];
    float a3 = M0[(4 * k4 + 3) * DD + col];
#pragma unroll
    for (int j = 0; j < 16; j++) {
      const float4 hv = *(const float4*)&hs[(half * 16 + j) * DD + 4 * k4];
      acc0[j] += hv.x * a0 + hv.y * a1 + hv.z * a2 + hv.w * a3;
    }
  }
  for (int j = 0; j < 16; j++) {
    int n = n0 + half * 16 + j;
    if (n < NN) outq[(size_t)n * DD + col] = acc0[j] + bias[col];
  }
}

// ---------------- PK pass: PKQ[n][2k,2k+1] = bf16(h@Ck0), bf16(h@Ck1) ----------------
__global__ void __launch_bounds__(256) k_matpk(
    const float* __restrict__ h, const float* __restrict__ M0,
    const float* __restrict__ M1, u16* __restrict__ pkq) {
  __shared__ float hs[32 * DD];
  int tid = threadIdx.x;
  int n0 = blockIdx.x * 32;
  for (int idx = tid; idx < 32 * DD; idx += 256) {
    int n = n0 + (idx >> 7);
    hs[idx] = (n < NN) ? h[(size_t)n * DD + (idx & 127)] : 0.0f;
  }
  __syncthreads();
  int col = tid & 127, half = tid >> 7;
  float acc0[16], acc1[16];
#pragma unroll
  for (int j = 0; j < 16; j++) { acc0[j] = 0.0f; acc1[j] = 0.0f; }
  for (int k4 = 0; k4 < DD / 4; k4++) {
    float a0 = M0[(4 * k4 + 0) * DD + col];
    float a1 = M0[(4 * k4 + 1) * DD + col];
    float a2 = M0[(4 * k4 + 2) * DD + col];
    float a3 = M0[(4 * k4 + 3) * DD + col];
    float b0 = M1[(4 * k4 + 0) * DD + col];
    float b1 = M1[(4 * k4 + 1) * DD + col];
    float b2 = M1[(4 * k4 + 2) * DD + col];
    float b3 = M1[(4 * k4 + 3) * DD + col];
#pragma unroll
    for (int j = 0; j < 16; j++) {
      const float4 hv = *(const float4*)&hs[(half * 16 + j) * DD + 4 * k4];
      acc0[j] += hv.x * a0 + hv.y * a1 + hv.z * a2 + hv.w * a3;
      acc1[j] += hv.x * b0 + hv.y * b1 + hv.z * b2 + hv.w * b3;
    }
  }
  for (int j = 0; j < 16; j++) {
    int n = n0 + half * 16 + j;
    if (n < NN) {
      ushort2 st;
      st.x = f2bf(acc0[j]);
      st.y = f2bf(acc1[j]);
      *(ushort2*)&pkq[(size_t)n * 384 + 2 * col] = st;
    }
  }
}

// ---------------- t0/t1: t_b[n] = (h[n]@Dk_b)·q[n] ----------------
__global__ void __launch_bounds__(256) k_matdot(
    const float* __restrict__ h, const float* __restrict__ M0,
    const float* __restrict__ M1, const float* __restrict__ q_in,
    float* __restrict__ outt0, float* __restrict__ outt1) {
  __shared__ float hs[32 * DD];
  __shared__ float red2[4][16][2];
  int tid = threadIdx.x;
  int n0 = blockIdx.x * 32;
  for (int idx = tid; idx < 32 * DD; idx += 256) {
    int n = n0 + (idx >> 7);
    hs[idx] = (n < NN) ? h[(size_t)n * DD + (idx & 127)] : 0.0f;
  }
  __syncthreads();
  int col = tid & 127, half = tid >> 7;
  int lane = tid & 63, wid = tid >> 6;
  float acc0[16], acc1[16];
#pragma unroll
  for (int j = 0; j < 16; j++) { acc0[j] = 0.0f; acc1[j] = 0.0f; }
  for (int k4 = 0; k4 < DD / 4; k4++) {
    float a0 = M0[(4 * k4 + 0) * DD + col];
    float a1 = M0[(4 * k4 + 1) * DD + col];
    float a2 = M0[(4 * k4 + 2) * DD + col];
    float a3 = M0[(4 * k4 + 3) * DD + col];
    float b0 = M1[(4 * k4 + 0) * DD + col];
    float b1 = M1[(4 * k4 + 1) * DD + col];
    float b2 = M1[(4 * k4 + 2) * DD + col];
    float b3 = M1[(4 * k4 + 3) * DD + col];
#pragma unroll
    for (int j = 0; j < 16; j++) {
      const float4 hv = *(const float4*)&hs[(half * 16 + j) * DD + 4 * k4];
      acc0[j] += hv.x * a0 + hv.y * a1 + hv.z * a2 + hv.w * a3;
      acc1[j] += hv.x * b0 + hv.y * b1 + hv.z * b2 + hv.w * b3;
    }
  }
#pragma unroll
  for (int j = 0; j < 16; j++) {
    int n = n0 + half * 16 + j;
    float qv = (n < NN) ? q_in[(size_t)n * DD + col] : 0.0f;
    float v0 = acc0[j] * qv, v1 = acc1[j] * qv;
    for (int off = 32; off; off >>= 1) {
      v0 += __shfl_xor(v0, off);
      v1 += __shfl_xor(v1, off);
    }
    if (lane == 0) { red2[wid][j][0] = v0; red2[wid][j][1] = v1; }
  }
  __syncthreads();
  if (tid < 32) {
    int j = tid & 15, g = tid >> 4;
    int n = n0 + g * 16 + j;
    if (n < NN) {
      outt0[n] = red2[g * 2][j][0] + red2[g * 2 + 1][j][0];
      outt1[n] = red2[g * 2][j][1] + red2[g * 2 + 1][j][1];
    }
  }
}

// ---------------- per-node scalars (+ bf16 pack of q into PKQ) ----------------
__global__ void k_nodescalars(const float* h, const float* q, const float* vecs,
                              const float* wkb, const float* coef, const float* wvb,
                              float* av0, float* av1, float* bv0, float* bv1,
                              float* u, float* selfy, u16* pkq) {
  int wid = threadIdx.x >> 6, lane = threadIdx.x & 63;
  int n = blockIdx.x * 4 + wid;
  if (n >= NN) return;
  const float* avv0 = vecs;
  const float* avv1 = vecs + DD;
  const float* bvv0 = vecs + 2 * DD;
  const float* bvv1 = vecs + 3 * DD;
  float h0 = h[(size_t)n * DD + lane], h1 = h[(size_t)n * DD + 64 + lane];
  float q0 = q[(size_t)n * DD + lane], q1 = q[(size_t)n * DD + 64 + lane];
  pkq[(size_t)n * 384 + 256 + lane] = f2bf(q0);
  pkq[(size_t)n * 384 + 256 + 64 + lane] = f2bf(q1);
  float a0 = h0 * avv0[lane] + h1 * avv0[64 + lane];
  float a1 = h0 * avv1[lane] + h1 * avv1[64 + lane];
  float b0 = h0 * bvv0[lane] + h1 * bvv0[64 + lane];
  float b1 = h0 * bvv1[lane] + h1 * bvv1[64 + lane];
  float uu = q0 * wkb[lane] + q1 * wkb[64 + lane];
  for (int off = 32; off; off >>= 1) {
    a0 += __shfl_xor(a0, off); a1 += __shfl_xor(a1, off);
    b0 += __shfl_xor(b0, off); b1 += __shfl_xor(b1, off);
    uu += __shfl_xor(uu, off);
  }
  if (lane == 0) {
    av0[n] = a0; av1[n] = a1; bv0[n] = b0; bv1[n] = b1; u[n] = uu;
    float c40 = coef[4 * 2 + 0], c41 = coef[4 * 2 + 1];
    selfy[n] = c40 * (a0 + b0) + c41 * (a1 + b1) + wvb[0];
  }
}

// ---------------- edge kernel: 16 lanes per edge ----------------
__global__ void __launch_bounds__(256) k_edges16(
    const int* __restrict__ src, const int* __restrict__ dst,
    const int* __restrict__ et, const float* __restrict__ coef,
    const float* __restrict__ wvb, const u16* __restrict__ pkq,
    const float* __restrict__ t0, const float* __restrict__ t1,
    const float* __restrict__ u, const float* __restrict__ av0,
    const float* __restrict__ av1, const float* __restrict__ bv0,
    const float* __restrict__ bv1, float* wvin, float* zin, float* wvout,
    float* zout) {
  int tid = threadIdx.x;
  int sub = tid & 15;
  int g = tid >> 4;  // 16 edges per block
  long e = (long)blockIdx.x * 16 + g;
  int s = src[e], d = dst[e], t = et[e];
  float c0 = coef[t * 2], c1 = coef[t * 2 + 1];
  const u16* rs = pkq + (size_t)s * 384;
  const u16* rd = pkq + (size_t)d * 384;
  u16x8 ps0 = *(const u16x8*)(rs + sub * 16);
  u16x8 ps1 = *(const u16x8*)(rs + sub * 16 + 8);
  u16x8 pd0 = *(const u16x8*)(rd + sub * 16);
  u16x8 pd1 = *(const u16x8*)(rd + sub * 16 + 8);
  u16x8 qs = *(const u16x8*)(rs + 256 + sub * 8);
  u16x8 qd = *(const u16x8*)(rd + 256 + sub * 8);
  float df = 0.0f, dr = 0.0f;
#pragma unroll
  for (int k = 0; k < 4; k++) {
    df += (c0 * bf2f(ps0[2 * k]) + c1 * bf2f(ps0[2 * k + 1])) * bf2f(qd[k]);
    dr += (c0 * bf2f(pd0[2 * k]) + c1 * bf2f(pd0[2 * k + 1])) * bf2f(qs[k]);
    df += (c0 * bf2f(ps1[2 * k]) + c1 * bf2f(ps1[2 * k + 1])) * bf2f(qd[4 + k]);
    dr += (c0 * bf2f(pd1[2 * k]) + c1 * bf2f(pd1[2 * k + 1])) * bf2f(qs[4 + k]);
  }
#pragma unroll
  for (int off = 8; off; off >>= 1) {
    df += __shfl_xor(df, off);
    dr += __shfl_xor(dr, off);
  }
  if (sub == 0) {
    const float scale = 11.3137084989847604f;  // sqrt(128)
    float wvbd = wvb[0];
    float sf = (df + c0 * t0[d] + c1 * t1[d] + u[d]) / scale;
    sf = fminf(fmaxf(sf, -10.0f), 10.0f);
    float ef = expf(sf);
    float nvf = c0 * (av0[s] + bv0[d]) + c1 * (av1[s] + bv1[d]) + wvbd;
    atomicAdd(&wvin[d], ef * nvf);
    atomicAdd(&zin[d], ef);
    float sr = (dr + c0 * t0[s] + c1 * t1[s] + u[s]) / scale;
    sr = fminf(fmaxf(sr, -10.0f), 10.0f);
    float er = expf(sr);
    float nvr = c0 * (av0[d] + bv0[s]) + c1 * (av1[d] + bv1[s]) + wvbd;
    atomicAdd(&wvout[s], er * nvr);
    atomicAdd(&zout[s], er);
  }
}

// ---------------- y + key + histogram ----------------
__device__ inline unsigned fkey(float f) {
  unsigned b = __float_as_uint(f);
  return (b & 0x80000000u) ? ~b : (b | 0x80000000u);
}

__global__ void k_y(const float* wvin, const float* zin, const float* wvout,
                    const float* zout, const float* selfy, float* y, unsigned* ykey,
                    int* hist) {
  int n = blockIdx.x * blockDim.x + threadIdx.x;
  if (n < NN) {
    float v = wvin[n] / (zin[n] + 1e-6f) + wvout[n] / (zout[n] + 1e-6f) + selfy[n];
    y[n] = v;
    unsigned k = fkey(v);
    ykey[n] = k;
    atomicAdd(&hist[k >> 18], 1);
  }
}

// ---------------- suffix sum over 16384 bins: suff[b] = sum_{b'>b} hist[b'] ----------------
__global__ void k_scanhist(const int* __restrict__ hist, int* __restrict__ suff) {
  __shared__ int sh[256];
  __shared__ int carry;
  int t = threadIdx.x;
  if (t == 0) carry = 0;
  __syncthreads();
  for (int s = 0; s < NBIN / 256; s++) {
    int b = NBIN - 1 - (s * 256 + t);  // descending bins
    int v = hist[b];
    sh[t] = v;
    __syncthreads();
    for (int off = 1; off < 256; off <<= 1) {
      int u2 = (t >= off) ? sh[t - off] : 0;
      __syncthreads();
      sh[t] += u2;
      __syncthreads();
    }
    suff[b] = carry + sh[t] - v;  // exclusive over higher bins
    __syncthreads();
    if (t == 0) carry += sh[255];
    __syncthreads();
  }
}

// ---------------- scatter bin member lists ----------------
__global__ void k_scatmem(const unsigned* __restrict__ ykey, const int* __restrict__ suff,
                          int* __restrict__ cur, int* __restrict__ binlist) {
  int i = blockIdx.x * 256 + threadIdx.x;
  if (i >= NN) return;
  int b = ykey[i] >> 18;
  int slot = suff[b] + atomicAdd(&cur[b], 1);
  binlist[slot] = i;
}

// ---------------- exact rank within bin ----------------
__global__ void k_rankbin(const unsigned* __restrict__ ykey, const int* __restrict__ suff,
                          const int* __restrict__ hist, const int* __restrict__ binlist,
                          int* __restrict__ rank) {
  int i = blockIdx.x * 256 + threadIdx.x;
  if (i >= NN) return;
  unsigned ki = ykey[i];
  int b = ki >> 18;
  int base = suff[b];
  int end = base + hist[b];
  int cnt = 0;
  for (int s = base; s < end; s++) {
    int j = binlist[s];
    unsigned kj = ykey[j];
    cnt += (kj > ki || (kj == ki && j < i)) ? 1 : 0;
  }
  rank[i] = base + cnt;
}

// ---------------- selection scatter ----------------
__global__ void k_bcnt(const int* rank, int* bcnt) {
  __shared__ int sh[256];
  int i = blockIdx.x * 256 + threadIdx.x;
  int f = (i < NN && rank[i] < KK) ? 1 : 0;
  sh[threadIdx.x] = f;
  __syncthreads();
  for (int off = 128; off; off >>= 1) {
    if (threadIdx.x < off) sh[threadIdx.x] += sh[threadIdx.x + off];
    __syncthreads();
  }
  if (threadIdx.x == 0) bcnt[blockIdx.x] = sh[0];
}

__global__ void k_scan(int* bcnt, int nb) {
  __shared__ int sh[256];
  int t = threadIdx.x;
  int v = (t < nb) ? bcnt[t] : 0;
  sh[t] = v;
  __syncthreads();
  for (int off = 1; off < 256; off <<= 1) {
    int u2 = (t >= off) ? sh[t - off] : 0;
    __syncthreads();
    sh[t] += u2;
    __syncthreads();
  }
  if (t < nb) bcnt[t] = sh[t] - v;  // exclusive
}

__global__ void k_scatter(const int* rank, const int* bcnt, const float* y,
                          float* out_ids, int* selp, float* sig) {
  __shared__ int sh[256];
  int i = blockIdx.x * 256 + threadIdx.x;
  int f = (i < NN && rank[i] < KK) ? 1 : 0;
  sh[threadIdx.x] = f;
  __syncthreads();
  for (int off = 1; off < 256; off <<= 1) {
    int v = (threadIdx.x >= off) ? sh[threadIdx.x - off] : 0;
    __syncthreads();
    sh[threadIdx.x] += v;
    __syncthreads();
  }
  if (f) {
    int slot = bcnt[blockIdx.x] + sh[threadIdx.x] - 1;
    out_ids[slot] = (float)i;
    int p = rank[i];  // position in descending-y list = sel index (faithful quirk)
    selp[slot] = p;
    sig[slot] = 1.0f / (1.0f + expf(-y[p]));
  }
}

__global__ void k_outh(const float* h, const int* selp, const float* sig, float* out) {
  long idx = (long)blockIdx.x * 256 + threadIdx.x;
  if (idx >= (long)KK * DD) return;
  int slot = (int)(idx >> 7), c = (int)(idx & 127);
  int p = selp[slot];
  out[KK + idx] = h[(size_t)p * DD + c] * sig[slot];
}

extern "C" void kernel_launch(void* const* d_in, const int* in_sizes, int n_in,
                              void* d_out, int out_size, void* d_ws, size_t ws_size,
                              hipStream_t stream) {
  const float* h = (const float*)d_in[0];
  const int* src = (const int*)d_in[1];
  const int* dst = (const int*)d_in[2];
  const int* etype = (const int*)d_in[3];
  const float* Wb = (const float*)d_in[4];
  const float* coef = (const float*)d_in[5];
  const float* wqw = (const float*)d_in[6];
  const float* wqb = (const float*)d_in[7];
  const float* wkw = (const float*)d_in[8];
  const float* wkb = (const float*)d_in[9];
  const float* wvw = (const float*)d_in[10];
  const float* wvb = (const float*)d_in[11];
  float* out = (float*)d_out;

  float* W = (float*)d_ws;
  size_t o = 0;
  float* q = W + o;    o += (size_t)NN * DD;
  u16* PKQ = (u16*)(W + o); o += (size_t)NN * 192;  // u16 [n][384]: pk01 interleaved + qe
  float* Ck0 = W + o;  o += DD * DD;
  float* Ck1 = W + o;  o += DD * DD;
  float* Dk0 = W + o;  o += DD * DD;
  float* Dk1 = W + o;  o += DD * DD;
  float* vecs = W + o; o += 4 * DD;
  float* t0 = W + o;   o += NN;
  float* t1 = W + o;   o += NN;
  float* av0 = W + o;  o += NN;
  float* av1 = W + o;  o += NN;
  float* bv0 = W + o;  o += NN;
  float* bv1 = W + o;  o += NN;
  float* u = W + o;    o += NN;
  float* selfy = W + o; o += NN;
  float* wvin = W + o;  o += NN;  // zero region start (4*NN contiguous)
  float* zin = W + o;   o += NN;
  float* wvout = W + o; o += NN;
  float* zout = W + o;  o += NN;
  float* y = W + o;     o += NN;
  unsigned* ykey = (unsigned*)(W + o); o += NN;
  float* sig = W + o;   o += KK;
  int* ibase = (int*)(W + o);
  int* rank = ibase;
  int* bcnt = ibase + NN;
  int* selp = ibase + NN + 256;
  int* hist = ibase + 2 * NN + 256;   // zero region: hist + cur contiguous
  int* cur = hist + NBIN;
  int* suff = cur + NBIN;
  int* binlist = suff + NBIN;

  int nb = (NN + 255) / 256;  // 196
  int gx = (NN + 31) / 32;    // 1563

  k_zero<<<256, 256, 0, stream>>>(wvin, 4 * NN, hist, 2 * NBIN);
  k_smallmats<<<68, 256, 0, stream>>>(Wb, wkw, wvw, Ck0, Ck1, Dk0, Dk1, vecs);
  k_matq<<<gx, 256, 0, stream>>>(h, wqw, wqb, q);
  k_matpk<<<gx, 256, 0, stream>>>(h, Ck0, Ck1, PKQ);
  k_matdot<<<gx, 256, 0, stream>>>(h, Dk0, Dk1, q, t0, t1);
  k_nodescalars<<<(NN + 3) / 4, 256, 0, stream>>>(h, q, vecs, wkb, coef, wvb, av0, av1,
                                                  bv0, bv1, u, selfy, PKQ);
  k_edges16<<<NE / 16, 256, 0, stream>>>(src, dst, etype, coef, wvb, PKQ, t0, t1, u,
                                         av0, av1, bv0, bv1, wvin, zin, wvout, zout);
  k_y<<<nb, 256, 0, stream>>>(wvin, zin, wvout, zout, selfy, y, ykey, hist);
  k_scanhist<<<1, 256, 0, stream>>>(hist, suff);
  k_scatmem<<<nb, 256, 0, stream>>>(ykey, suff, cur, binlist);
  k_rankbin<<<nb, 256, 0, stream>>>(ykey, suff, hist, binlist, rank);
  k_bcnt<<<nb, 256, 0, stream>>>(rank, bcnt);
  k_scan<<<1, 256, 0, stream>>>(bcnt, nb);
  k_scatter<<<nb, 256, 0, stream>>>(rank, bcnt, y, out, selp, sig);
  k_outh<<<(KK * DD) / 256, 256, 0, stream>>>(h, selp, sig, out);
}

// Round 6
// 517.069 us; speedup vs baseline: 1.7581x; 1.3214x over previous
//
#include <hip/hip_runtime.h>

#define NN 50000
#define NE 500000
#define DD 128
#define KK 25000
#define NBIN 16384

typedef unsigned short u16;
typedef __attribute__((ext_vector_type(8))) unsigned short u16x8;

__device__ inline u16 f2bf(float x) {
  unsigned u = __float_as_uint(x);
  unsigned r = (u + 0x7FFFu + ((u >> 16) & 1u)) >> 16;
  return (u16)r;
}
__device__ inline float bf2f(u16 b) {
  return __uint_as_float(((unsigned)b) << 16);
}

// ---------------- zero init ----------------
__global__ void k_zero(float* zf, int nf, int* zi, int ni) {
  int i = blockIdx.x * blockDim.x + threadIdx.x;
  int stride = gridDim.x * blockDim.x;
  for (int k = i; k < nf; k += stride) zf[k] = 0.0f;
  for (int k = i; k < ni; k += stride) zi[k] = 0;
}

// ---------------- small composed matrices (f32), 68 blocks ----------------
__global__ void k_smallmats(const float* __restrict__ Wb, const float* __restrict__ wkw,
                            const float* __restrict__ wvw, float* Ck0, float* Ck1,
                            float* Dk0, float* Dk1, float* vecs) {
  int b = blockIdx.x, tid = threadIdx.x;
  if (b < 64) {
    int mat = b >> 4;
    int basis = mat & 1;
    int rowoff = (mat >> 1) * DD;
    float* outp = (mat == 0) ? Ck0 : ((mat == 1) ? Ck1 : ((mat == 2) ? Dk0 : Dk1));
    int i = (b & 15) * 2 + (tid >> 7);
    int t = tid & 127;
    const float* wrow = Wb + (size_t)(basis * 2 * DD + rowoff + i) * DD;
    float s = 0.0f;
    for (int m = 0; m < DD; m++) s += wrow[m] * wkw[m * DD + t];
    outp[i * DD + t] = s;
  } else if (b < 68) {
    int which = b - 64;
    int basis = which & 1, rowoff = (which >> 1) * DD;
    if (tid < DD) {
      const float* wrow = Wb + (size_t)(basis * 2 * DD + rowoff + tid) * DD;
      float s = 0.0f;
      for (int m = 0; m < DD; m++) s += wrow[m] * wvw[m];
      vecs[which * DD + tid] = s;
    }
  }
}

// ---------------- fused node pass ----------------
// Per node n: q = h@wqw+wqb (bf16 into PKQ + used for dots)
//             pk_b = h@Ck_b (bf16 interleaved into PKQ)
//             t_b  = (h@Dk_b)·q, u = q·wkb
//             av_b = h·avv_b, bv_b = h·bvv_b, selfy = c40(av0+bv0)+c41(av1+bv1)+wvb
#define NPB 16  // nodes per block
__global__ void __launch_bounds__(256) k_nodeA(
    const float* __restrict__ h, const float* __restrict__ Mq,
    const float* __restrict__ C0, const float* __restrict__ C1,
    const float* __restrict__ D0, const float* __restrict__ D1,
    const float* __restrict__ wqb, const float* __restrict__ wkb,
    const float* __restrict__ vecs, const float* __restrict__ coef,
    const float* __restrict__ wvb, u16* __restrict__ pkq,
    float* __restrict__ t0o, float* __restrict__ t1o, float* __restrict__ uo,
    float* __restrict__ av0o, float* __restrict__ av1o, float* __restrict__ bv0o,
    float* __restrict__ bv1o, float* __restrict__ selfyo) {
  __shared__ float hs[NPB * DD];
  __shared__ float red[4][8][7];
  int tid = threadIdx.x;
  int n0 = blockIdx.x * NPB;
  for (int idx = tid; idx < NPB * DD; idx += 256) {
    int n = n0 + (idx >> 7);
    hs[idx] = (n < NN) ? h[(size_t)n * DD + (idx & 127)] : 0.0f;
  }
  __syncthreads();
  int col = tid & 127, half = tid >> 7;
  int lane = tid & 63, wid = tid >> 6;
  float aq[8], ap0[8], ap1[8], ad0[8], ad1[8];
#pragma unroll
  for (int j = 0; j < 8; j++) { aq[j] = 0.f; ap0[j] = 0.f; ap1[j] = 0.f; ad0[j] = 0.f; ad1[j] = 0.f; }
  for (int k4 = 0; k4 < DD / 4; k4++) {
    float q0 = Mq[(4 * k4 + 0) * DD + col], q1 = Mq[(4 * k4 + 1) * DD + col];
    float q2 = Mq[(4 * k4 + 2) * DD + col], q3 = Mq[(4 * k4 + 3) * DD + col];
    float c00 = C0[(4 * k4 + 0) * DD + col], c01 = C0[(4 * k4 + 1) * DD + col];
    float c02 = C0[(4 * k4 + 2) * DD + col], c03 = C0[(4 * k4 + 3) * DD + col];
    float c10 = C1[(4 * k4 + 0) * DD + col], c11 = C1[(4 * k4 + 1) * DD + col];
    float c12 = C1[(4 * k4 + 2) * DD + col], c13 = C1[(4 * k4 + 3) * DD + col];
    float d00 = D0[(4 * k4 + 0) * DD + col], d01 = D0[(4 * k4 + 1) * DD + col];
    float d02 = D0[(4 * k4 + 2) * DD + col], d03 = D0[(4 * k4 + 3) * DD + col];
    float d10 = D1[(4 * k4 + 0) * DD + col], d11 = D1[(4 * k4 + 1) * DD + col];
    float d12 = D1[(4 * k4 + 2) * DD + col], d13 = D1[(4 * k4 + 3) * DD + col];
#pragma unroll
    for (int j = 0; j < 8; j++) {
      const float4 hv = *(const float4*)&hs[(half * 8 + j) * DD + 4 * k4];
      aq[j] += hv.x * q0 + hv.y * q1 + hv.z * q2 + hv.w * q3;
      ap0[j] += hv.x * c00 + hv.y * c01 + hv.z * c02 + hv.w * c03;
      ap1[j] += hv.x * c10 + hv.y * c11 + hv.z * c12 + hv.w * c13;
      ad0[j] += hv.x * d00 + hv.y * d01 + hv.z * d02 + hv.w * d03;
      ad1[j] += hv.x * d10 + hv.y * d11 + hv.z * d12 + hv.w * d13;
    }
  }
  float bias = wqb[col];
  float wkbc = wkb[col];
  float va0 = vecs[col], va1 = vecs[DD + col], vb0 = vecs[2 * DD + col],
        vb1 = vecs[3 * DD + col];
#pragma unroll
  for (int j = 0; j < 8; j++) {
    int n = n0 + half * 8 + j;
    float qv = aq[j] + bias;
    float hc = hs[(half * 8 + j) * DD + col];
    if (n < NN) {
      ushort2 st;
      st.x = f2bf(ap0[j]);
      st.y = f2bf(ap1[j]);
      *(ushort2*)&pkq[(size_t)n * 384 + 2 * col] = st;
      pkq[(size_t)n * 384 + 256 + col] = f2bf(qv);
    }
    float v0 = ad0[j] * qv;
    float v1 = ad1[j] * qv;
    float vu = qv * wkbc;
    float a0 = hc * va0, a1 = hc * va1, b0 = hc * vb0, b1 = hc * vb1;
#pragma unroll
    for (int off = 32; off; off >>= 1) {
      v0 += __shfl_xor(v0, off);
      v1 += __shfl_xor(v1, off);
      vu += __shfl_xor(vu, off);
      a0 += __shfl_xor(a0, off);
      a1 += __shfl_xor(a1, off);
      b0 += __shfl_xor(b0, off);
      b1 += __shfl_xor(b1, off);
    }
    if (lane == 0) {
      red[wid][j][0] = v0; red[wid][j][1] = v1; red[wid][j][2] = vu;
      red[wid][j][3] = a0; red[wid][j][4] = a1; red[wid][j][5] = b0;
      red[wid][j][6] = b1;
    }
  }
  __syncthreads();
  if (tid < 16) {
    int j = tid & 7, g = tid >> 3;
    int n = n0 + g * 8 + j;
    if (n < NN) {
      int w0 = 2 * g, w1 = 2 * g + 1;
      float t0 = red[w0][j][0] + red[w1][j][0];
      float t1 = red[w0][j][1] + red[w1][j][1];
      float uu = red[w0][j][2] + red[w1][j][2];
      float a0 = red[w0][j][3] + red[w1][j][3];
      float a1 = red[w0][j][4] + red[w1][j][4];
      float b0 = red[w0][j][5] + red[w1][j][5];
      float b1 = red[w0][j][6] + red[w1][j][6];
      t0o[n] = t0; t1o[n] = t1; uo[n] = uu;
      av0o[n] = a0; av1o[n] = a1; bv0o[n] = b0; bv1o[n] = b1;
      float c40 = coef[4 * 2 + 0], c41 = coef[4 * 2 + 1];
      selfyo[n] = c40 * (a0 + b0) + c41 * (a1 + b1) + wvb[0];
    }
  }
}

// ---------------- edge kernel: 16 lanes per edge ----------------
__global__ void __launch_bounds__(256) k_edges16(
    const int* __restrict__ src, const int* __restrict__ dst,
    const int* __restrict__ et, const float* __restrict__ coef,
    const float* __restrict__ wvb, const u16* __restrict__ pkq,
    const float* __restrict__ t0, const float* __restrict__ t1,
    const float* __restrict__ u, const float* __restrict__ av0,
    const float* __restrict__ av1, const float* __restrict__ bv0,
    const float* __restrict__ bv1, float* wvin, float* zin, float* wvout,
    float* zout) {
  int tid = threadIdx.x;
  int sub = tid & 15;
  int g = tid >> 4;  // 16 edges per block
  long e = (long)blockIdx.x * 16 + g;
  int s = src[e], d = dst[e], t = et[e];
  float c0 = coef[t * 2], c1 = coef[t * 2 + 1];
  const u16* rs = pkq + (size_t)s * 384;
  const u16* rd = pkq + (size_t)d * 384;
  u16x8 ps0 = *(const u16x8*)(rs + sub * 16);
  u16x8 ps1 = *(const u16x8*)(rs + sub * 16 + 8);
  u16x8 pd0 = *(const u16x8*)(rd + sub * 16);
  u16x8 pd1 = *(const u16x8*)(rd + sub * 16 + 8);
  u16x8 qs = *(const u16x8*)(rs + 256 + sub * 8);
  u16x8 qd = *(const u16x8*)(rd + 256 + sub * 8);
  float df = 0.0f, dr = 0.0f;
#pragma unroll
  for (int k = 0; k < 4; k++) {
    df += (c0 * bf2f(ps0[2 * k]) + c1 * bf2f(ps0[2 * k + 1])) * bf2f(qd[k]);
    dr += (c0 * bf2f(pd0[2 * k]) + c1 * bf2f(pd0[2 * k + 1])) * bf2f(qs[k]);
    df += (c0 * bf2f(ps1[2 * k]) + c1 * bf2f(ps1[2 * k + 1])) * bf2f(qd[4 + k]);
    dr += (c0 * bf2f(pd1[2 * k]) + c1 * bf2f(pd1[2 * k + 1])) * bf2f(qs[4 + k]);
  }
#pragma unroll
  for (int off = 8; off; off >>= 1) {
    df += __shfl_xor(df, off);
    dr += __shfl_xor(dr, off);
  }
  if (sub == 0) {
    const float scale = 11.3137084989847604f;  // sqrt(128)
    float wvbd = wvb[0];
    float sf = (df + c0 * t0[d] + c1 * t1[d] + u[d]) / scale;
    sf = fminf(fmaxf(sf, -10.0f), 10.0f);
    float ef = expf(sf);
    float nvf = c0 * (av0[s] + bv0[d]) + c1 * (av1[s] + bv1[d]) + wvbd;
    atomicAdd(&wvin[d], ef * nvf);
    atomicAdd(&zin[d], ef);
    float sr = (dr + c0 * t0[s] + c1 * t1[s] + u[s]) / scale;
    sr = fminf(fmaxf(sr, -10.0f), 10.0f);
    float er = expf(sr);
    float nvr = c0 * (av0[d] + bv0[s]) + c1 * (av1[d] + bv1[s]) + wvbd;
    atomicAdd(&wvout[s], er * nvr);
    atomicAdd(&zout[s], er);
  }
}

// ---------------- y + key + histogram ----------------
__device__ inline unsigned fkey(float f) {
  unsigned b = __float_as_uint(f);
  return (b & 0x80000000u) ? ~b : (b | 0x80000000u);
}

__global__ void k_y(const float* wvin, const float* zin, const float* wvout,
                    const float* zout, const float* selfy, float* y, unsigned* ykey,
                    int* hist) {
  int n = blockIdx.x * blockDim.x + threadIdx.x;
  if (n < NN) {
    float v = wvin[n] / (zin[n] + 1e-6f) + wvout[n] / (zout[n] + 1e-6f) + selfy[n];
    y[n] = v;
    unsigned k = fkey(v);
    ykey[n] = k;
    atomicAdd(&hist[k >> 18], 1);
  }
}

// ---------------- histogram block sums (64 blocks) ----------------
__global__ void k_hsum(const int* __restrict__ hist, int* __restrict__ bsum) {
  __shared__ int sh[256];
  int t = threadIdx.x;
  sh[t] = hist[blockIdx.x * 256 + t];
  __syncthreads();
  for (int off = 128; off; off >>= 1) {
    if (t < off) sh[t] += sh[t + off];
    __syncthreads();
  }
  if (t == 0) bsum[blockIdx.x] = sh[0];
}

// ---------------- per-bin exclusive suffix sum (64 blocks) ----------------
__global__ void k_hfinal(const int* __restrict__ hist, const int* __restrict__ bsum,
                         int* __restrict__ suff) {
  __shared__ int sh[256];
  __shared__ int carry;
  int t = threadIdx.x;
  int bx = blockIdx.x;
  if (t < 64) {
    int m = (t > bx) ? bsum[t] : 0;
#pragma unroll
    for (int off = 32; off; off >>= 1) m += __shfl_xor(m, off);
    if (t == 0) carry = m;
  }
  int base = bx * 256;
  int own = hist[base + 255 - t];  // reversed order for ascending scan
  sh[t] = own;
  __syncthreads();
  for (int off = 1; off < 256; off <<= 1) {
    int v = (t >= off) ? sh[t - off] : 0;
    __syncthreads();
    sh[t] += v;
    __syncthreads();
  }
  suff[base + 255 - t] = carry + sh[t] - own;
}

// ---------------- scatter bin member lists ----------------
__global__ void k_scatmem(const unsigned* __restrict__ ykey, const int* __restrict__ suff,
                          int* __restrict__ cur, int* __restrict__ binlist) {
  int i = blockIdx.x * 256 + threadIdx.x;
  if (i >= NN) return;
  int b = ykey[i] >> 18;
  int slot = suff[b] + atomicAdd(&cur[b], 1);
  binlist[slot] = i;
}

// ---------------- exact rank within bin ----------------
__global__ void k_rankbin(const unsigned* __restrict__ ykey, const int* __restrict__ suff,
                          const int* __restrict__ hist, const int* __restrict__ binlist,
                          int* __restrict__ rank) {
  int i = blockIdx.x * 256 + threadIdx.x;
  if (i >= NN) return;
  unsigned ki = ykey[i];
  int b = ki >> 18;
  int base = suff[b];
  int end = base + hist[b];
  int cnt = 0;
  for (int s = base; s < end; s++) {
    int j = binlist[s];
    unsigned kj = ykey[j];
    cnt += (kj > ki || (kj == ki && j < i)) ? 1 : 0;
  }
  rank[i] = base + cnt;
}

// ---------------- selection scatter ----------------
__global__ void k_bcnt(const int* rank, int* bcnt) {
  __shared__ int sh[256];
  int i = blockIdx.x * 256 + threadIdx.x;
  int f = (i < NN && rank[i] < KK) ? 1 : 0;
  sh[threadIdx.x] = f;
  __syncthreads();
  for (int off = 128; off; off >>= 1) {
    if (threadIdx.x < off) sh[threadIdx.x] += sh[threadIdx.x + off];
    __syncthreads();
  }
  if (threadIdx.x == 0) bcnt[blockIdx.x] = sh[0];
}

__global__ void k_scan(int* bcnt, int nb) {
  __shared__ int sh[256];
  int t = threadIdx.x;
  int v = (t < nb) ? bcnt[t] : 0;
  sh[t] = v;
  __syncthreads();
  for (int off = 1; off < 256; off <<= 1) {
    int u2 = (t >= off) ? sh[t - off] : 0;
    __syncthreads();
    sh[t] += u2;
    __syncthreads();
  }
  if (t < nb) bcnt[t] = sh[t] - v;  // exclusive
}

__global__ void k_scatter(const int* rank, const int* bcnt, const float* y,
                          float* out_ids, int* selp, float* sig) {
  __shared__ int sh[256];
  int i = blockIdx.x * 256 + threadIdx.x;
  int f = (i < NN && rank[i] < KK) ? 1 : 0;
  sh[threadIdx.x] = f;
  __syncthreads();
  for (int off = 1; off < 256; off <<= 1) {
    int v = (threadIdx.x >= off) ? sh[threadIdx.x - off] : 0;
    __syncthreads();
    sh[threadIdx.x] += v;
    __syncthreads();
  }
  if (f) {
    int slot = bcnt[blockIdx.x] + sh[threadIdx.x] - 1;
    out_ids[slot] = (float)i;
    int p = rank[i];  // position in descending-y list = sel index (faithful quirk)
    selp[slot] = p;
    sig[slot] = 1.0f / (1.0f + expf(-y[p]));
  }
}

__global__ void k_outh(const float* h, const int* selp, const float* sig, float* out) {
  long idx = (long)blockIdx.x * 256 + threadIdx.x;
  if (idx >= (long)KK * DD) return;
  int slot = (int)(idx >> 7), c = (int)(idx & 127);
  int p = selp[slot];
  out[KK + idx] = h[(size_t)p * DD + c] * sig[slot];
}

extern "C" void kernel_launch(void* const* d_in, const int* in_sizes, int n_in,
                              void* d_out, int out_size, void* d_ws, size_t ws_size,
                              hipStream_t stream) {
  const float* h = (const float*)d_in[0];
  const int* src = (const int*)d_in[1];
  const int* dst = (const int*)d_in[2];
  const int* etype = (const int*)d_in[3];
  const float* Wb = (const float*)d_in[4];
  const float* coef = (const float*)d_in[5];
  const float* wqw = (const float*)d_in[6];
  const float* wqb = (const float*)d_in[7];
  const float* wkw = (const float*)d_in[8];
  const float* wkb = (const float*)d_in[9];
  const float* wvw = (const float*)d_in[10];
  const float* wvb = (const float*)d_in[11];
  float* out = (float*)d_out;

  float* W = (float*)d_ws;
  size_t o = 0;
  u16* PKQ = (u16*)(W + o); o += (size_t)NN * 192;  // u16 [n][384]: pk interleaved + q
  float* Ck0 = W + o;  o += DD * DD;
  float* Ck1 = W + o;  o += DD * DD;
  float* Dk0 = W + o;  o += DD * DD;
  float* Dk1 = W + o;  o += DD * DD;
  float* vecs = W + o; o += 4 * DD;
  float* t0 = W + o;   o += NN;
  float* t1 = W + o;   o += NN;
  float* av0 = W + o;  o += NN;
  float* av1 = W + o;  o += NN;
  float* bv0 = W + o;  o += NN;
  float* bv1 = W + o;  o += NN;
  float* u = W + o;    o += NN;
  float* selfy = W + o; o += NN;
  float* wvin = W + o;  o += NN;  // zero region start (4*NN contiguous)
  float* zin = W + o;   o += NN;
  float* wvout = W + o; o += NN;
  float* zout = W + o;  o += NN;
  float* y = W + o;     o += NN;
  unsigned* ykey = (unsigned*)(W + o); o += NN;
  float* sig = W + o;   o += KK;
  int* ibase = (int*)(W + o);
  int* rank = ibase;
  int* bcnt = ibase + NN;
  int* selp = ibase + NN + 256;
  int* hist = ibase + 2 * NN + 256;   // zero region: hist + cur contiguous
  int* cur = hist + NBIN;
  int* suff = cur + NBIN;
  int* bsum = suff + NBIN;
  int* binlist = bsum + 64;

  int nb = (NN + 255) / 256;  // 196

  k_zero<<<256, 256, 0, stream>>>(wvin, 4 * NN, hist, 2 * NBIN);
  k_smallmats<<<68, 256, 0, stream>>>(Wb, wkw, wvw, Ck0, Ck1, Dk0, Dk1, vecs);
  k_nodeA<<<(NN + NPB - 1) / NPB, 256, 0, stream>>>(
      h, wqw, Ck0, Ck1, Dk0, Dk1, wqb, wkb, vecs, coef, wvb, PKQ, t0, t1, u,
      av0, av1, bv0, bv1, selfy);
  k_edges16<<<NE / 16, 256, 0, stream>>>(src, dst, etype, coef, wvb, PKQ, t0, t1, u,
                                         av0, av1, bv0, bv1, wvin, zin, wvout, zout);
  k_y<<<nb, 256, 0, stream>>>(wvin, zin, wvout, zout, selfy, y, ykey, hist);
  k_hsum<<<64, 256, 0, stream>>>(hist, bsum);
  k_hfinal<<<64, 256, 0, stream>>>(hist, bsum, suff);
  k_scatmem<<<nb, 256, 0, stream>>>(ykey, suff, cur, binlist);
  k_rankbin<<<nb, 256, 0, stream>>>(ykey, suff, hist, binlist, rank);
  k_bcnt<<<nb, 256, 0, stream>>>(rank, bcnt);
  k_scan<<<1, 256, 0, stream>>>(bcnt, nb);
  k_scatter<<<nb, 256, 0, stream>>>(rank, bcnt, y, out, selp, sig);
  k_outh<<<(KK * DD) / 256, 256, 0, stream>>>(h, selp, sig, out);
}

// Round 8
// 494.624 us; speedup vs baseline: 1.8379x; 1.0454x over previous
//
#include <hip/hip_runtime.h>

#define NN 50000
#define NE 500000
#define DD 128
#define KK 25000
#define NBIN 16384
#define HP 136  // padded f16 LDS row

typedef _Float16 f16;
typedef __attribute__((ext_vector_type(8))) _Float16 f16x8;
typedef __attribute__((ext_vector_type(4))) float f32x4;

// ---------------- zero init ----------------
__global__ void k_zero(float* zf, int nf, int* zi, int ni) {
  int i = blockIdx.x * blockDim.x + threadIdx.x;
  int stride = gridDim.x * blockDim.x;
  for (int k = i; k < nf; k += stride) zf[k] = 0.0f;
  for (int k = i; k < ni; k += stride) zi[k] = 0;
}

// ---------------- combined weight matrix in MFMA B-frag layout ----------------
// Wc[k][gcol], gcol: 0-127 wqw | 128-255 Ck0 | 256-383 Ck1 | 384-511 Dk0 | 512-639 Dk1
// frag layout: Wcs[((ct*4+kc)*64 + lane)*8 + e] = Wc[kc*32 + (lane>>4)*8 + e][ct*16 + (lane&15)]
__global__ void k_smallmats2(const float* __restrict__ Wb, const float* __restrict__ wqw,
                             const float* __restrict__ wkw, const float* __restrict__ wvw,
                             f16* __restrict__ Wcs, float* __restrict__ vecs) {
  int idx = blockIdx.x * 256 + threadIdx.x;
  if (idx < 640 * 128) {
    int gcol = idx >> 7, k = idx & 127;
    float val;
    if (gcol < 128) {
      val = wqw[k * DD + gcol];
    } else {
      int part = (gcol - 128) >> 7;  // 0:Ck0 1:Ck1 2:Dk0 3:Dk1
      int c = (gcol - 128) & 127;
      int basis = part & 1;
      int rowoff = (part >> 1) * DD;
      const float* wrow = Wb + (size_t)(basis * 2 * DD + rowoff + k) * DD;
      float s = 0.f;
      for (int m = 0; m < DD; m++) s += wrow[m] * wkw[m * DD + c];
      val = s;
    }
    int ct = gcol >> 4, cl = gcol & 15, kc = k >> 5, kr = k & 31;
    int lane = (kr >> 3) * 16 + cl, e = kr & 7;
    Wcs[(size_t)(((ct * 4 + kc) * 64 + lane) * 8 + e)] = (f16)val;
  } else if (idx < 640 * 128 + 512) {
    int j = idx - 640 * 128;
    int which = j >> 7, i = j & 127;
    int basis = which & 1, rowoff = (which >> 1) * DD;
    const float* wrow = Wb + (size_t)(basis * 2 * DD + rowoff + i) * DD;
    float s = 0.f;
    for (int m = 0; m < DD; m++) s += wrow[m] * wvw[m];
    vecs[j] = s;
  }
}

// ---------------- MFMA node pass: 32 nodes/block, 4 waves ----------------
// outputs: PKQ[n][384] f16 = {pk0[128] | pk1[128] | q[128]}, t0,t1,u,av*,bv*,selfy
__global__ void __launch_bounds__(256) k_nodeMM(
    const float* __restrict__ h, const f16* __restrict__ Wcs,
    const float* __restrict__ wqb, const float* __restrict__ wkb,
    const float* __restrict__ vecs, const float* __restrict__ coef,
    const float* __restrict__ wvb, f16* __restrict__ pkq, float* __restrict__ t0o,
    float* __restrict__ t1o, float* __restrict__ uo, float* __restrict__ av0o,
    float* __restrict__ av1o, float* __restrict__ bv0o, float* __restrict__ bv1o,
    float* __restrict__ selfyo) {
  __shared__ f16 hsF[32 * HP];
  __shared__ float qL[32][132];
  int tid = threadIdx.x;
  int n0 = blockIdx.x * 32;
  for (int idx = tid; idx < 32 * DD; idx += 256) {
    int r = idx >> 7, c = idx & 127;
    int n = n0 + r;
    float v = (n < NN) ? h[(size_t)n * DD + c] : 0.f;
    hsF[r * HP + c] = (f16)v;
  }
  __syncthreads();
  int lane = tid & 63, wid = tid >> 6;
  int nh = wid & 1;            // node half
  int ctb = (wid >> 1) * 20;   // col-tile base
  int cl = lane & 15, kq = lane >> 4;
  int base_node = 16 * nh;

  f16x8 afr[4];
#pragma unroll
  for (int kc = 0; kc < 4; kc++)
    afr[kc] = *(const f16x8*)&hsF[(base_node + cl) * HP + kc * 32 + kq * 8];

  f32x4 acc[20];
#pragma unroll
  for (int t = 0; t < 20; t++) acc[t] = (f32x4){0.f, 0.f, 0.f, 0.f};

  const f16x8* Wf = (const f16x8*)Wcs;
#pragma unroll
  for (int t = 0; t < 20; t++) {
    int ct = ctb + t;
#pragma unroll
    for (int kc = 0; kc < 4; kc++) {
      f16x8 bfr = Wf[(ct * 4 + kc) * 64 + lane];
      acc[t] = __builtin_amdgcn_mfma_f32_16x16x32_f16(afr[kc], bfr, acc[t], 0, 0, 0);
    }
  }

  // ---- epilogue pass 1: q / pk0 / pk1 stores, qL, u partials ----
  float upart[4] = {0.f, 0.f, 0.f, 0.f};
#pragma unroll
  for (int t = 0; t < 20; t++) {
    int ct = ctb + t;
    int gc = ct * 16 + cl;
    if (ct < 8) {
      float wq = wqb[gc], wk = wkb[gc];
#pragma unroll
      for (int r = 0; r < 4; r++) {
        int row = base_node + kq * 4 + r;
        float qv = acc[t][r] + wq;
        qL[row][gc] = qv;
        int n = n0 + row;
        if (n < NN) pkq[(size_t)n * 384 + 256 + gc] = (f16)qv;
        upart[r] += wk * qv;
      }
    } else if (ct < 16) {
#pragma unroll
      for (int r = 0; r < 4; r++) {
        int n = n0 + base_node + kq * 4 + r;
        if (n < NN) pkq[(size_t)n * 384 + (gc - 128)] = (f16)acc[t][r];
      }
    } else if (ct < 24) {
#pragma unroll
      for (int r = 0; r < 4; r++) {
        int n = n0 + base_node + kq * 4 + r;
        if (n < NN) pkq[(size_t)n * 384 + 128 + (gc - 256)] = (f16)acc[t][r];
      }
    }
  }
  if (ctb == 0) {
#pragma unroll
    for (int r = 0; r < 4; r++) {
#pragma unroll
      for (int off = 1; off < 16; off <<= 1) upart[r] += __shfl_xor(upart[r], off);
      int n = n0 + base_node + kq * 4 + r;
      if (cl == 0 && n < NN) uo[n] = upart[r];
    }
  }
  __syncthreads();
  // ---- epilogue pass 2: t_b = d_b . q (d-waves only) ----
  if (ctb == 20) {
    float tp0[4] = {0.f, 0.f, 0.f, 0.f}, tp1[4] = {0.f, 0.f, 0.f, 0.f};
#pragma unroll
    for (int t = 0; t < 20; t++) {
      int ct = ctb + t;
      int gc = ct * 16 + cl;
      if (ct >= 24 && ct < 32) {
#pragma unroll
        for (int r = 0; r < 4; r++)
          tp0[r] += acc[t][r] * qL[base_node + kq * 4 + r][gc - 384];
      } else if (ct >= 32) {
#pragma unroll
        for (int r = 0; r < 4; r++)
          tp1[r] += acc[t][r] * qL[base_node + kq * 4 + r][gc - 512];
      }
    }
#pragma unroll
    for (int r = 0; r < 4; r++) {
#pragma unroll
      for (int off = 1; off < 16; off <<= 1) {
        tp0[r] += __shfl_xor(tp0[r], off);
        tp1[r] += __shfl_xor(tp1[r], off);
      }
      int n = n0 + base_node + kq * 4 + r;
      if (cl == 0 && n < NN) { t0o[n] = tp0[r]; t1o[n] = tp1[r]; }
    }
  }
  // ---- av/bv/selfy from staged h ----
  int nn2 = tid >> 3, sub = tid & 7;
  float a0 = 0.f, a1 = 0.f, b0 = 0.f, b1 = 0.f;
  for (int c = sub * 16; c < sub * 16 + 16; c++) {
    float hv = (float)hsF[nn2 * HP + c];
    a0 += hv * vecs[c];
    a1 += hv * vecs[DD + c];
    b0 += hv * vecs[2 * DD + c];
    b1 += hv * vecs[3 * DD + c];
  }
#pragma unroll
  for (int off = 1; off < 8; off <<= 1) {
    a0 += __shfl_xor(a0, off);
    a1 += __shfl_xor(a1, off);
    b0 += __shfl_xor(b0, off);
    b1 += __shfl_xor(b1, off);
  }
  if (sub == 0) {
    int n = n0 + nn2;
    if (n < NN) {
      av0o[n] = a0; av1o[n] = a1; bv0o[n] = b0; bv1o[n] = b1;
      float c40 = coef[4 * 2 + 0], c41 = coef[4 * 2 + 1];
      selfyo[n] = c40 * (a0 + b0) + c41 * (a1 + b1) + wvb[0];
    }
  }
}

// ---------------- edge kernel: 16 lanes per edge, f16 rows ----------------
__global__ void __launch_bounds__(256) k_edges16(
    const int* __restrict__ src, const int* __restrict__ dst,
    const int* __restrict__ et, const float* __restrict__ coef,
    const float* __restrict__ wvb, const f16* __restrict__ pkq,
    const float* __restrict__ t0, const float* __restrict__ t1,
    const float* __restrict__ u, const float* __restrict__ av0,
    const float* __restrict__ av1, const float* __restrict__ bv0,
    const float* __restrict__ bv1, float* wvin, float* zin, float* wvout,
    float* zout) {
  int tid = threadIdx.x;
  int sub = tid & 15;
  int g = tid >> 4;
  long e = (long)blockIdx.x * 16 + g;
  int s = src[e], d = dst[e], t = et[e];
  float c0 = coef[t * 2], c1 = coef[t * 2 + 1];
  const f16* rs = pkq + (size_t)s * 384;
  const f16* rd = pkq + (size_t)d * 384;
  f16x8 p0s = *(const f16x8*)(rs + sub * 8);
  f16x8 p1s = *(const f16x8*)(rs + 128 + sub * 8);
  f16x8 qse = *(const f16x8*)(rs + 256 + sub * 8);
  f16x8 p0d = *(const f16x8*)(rd + sub * 8);
  f16x8 p1d = *(const f16x8*)(rd + 128 + sub * 8);
  f16x8 qde = *(const f16x8*)(rd + 256 + sub * 8);
  float df = 0.f, dr = 0.f;
#pragma unroll
  for (int j = 0; j < 8; j++) {
    df += (c0 * (float)p0s[j] + c1 * (float)p1s[j]) * (float)qde[j];
    dr += (c0 * (float)p0d[j] + c1 * (float)p1d[j]) * (float)qse[j];
  }
#pragma unroll
  for (int off = 8; off; off >>= 1) {
    df += __shfl_xor(df, off);
    dr += __shfl_xor(dr, off);
  }
  if (sub == 0) {
    const float scale = 11.3137084989847604f;  // sqrt(128)
    float wvbd = wvb[0];
    float sf = (df + c0 * t0[d] + c1 * t1[d] + u[d]) / scale;
    sf = fminf(fmaxf(sf, -10.0f), 10.0f);
    float ef = expf(sf);
    float nvf = c0 * (av0[s] + bv0[d]) + c1 * (av1[s] + bv1[d]) + wvbd;
    atomicAdd(&wvin[d], ef * nvf);
    atomicAdd(&zin[d], ef);
    float sr = (dr + c0 * t0[s] + c1 * t1[s] + u[s]) / scale;
    sr = fminf(fmaxf(sr, -10.0f), 10.0f);
    float er = expf(sr);
    float nvr = c0 * (av0[d] + bv0[s]) + c1 * (av1[d] + bv1[s]) + wvbd;
    atomicAdd(&wvout[s], er * nvr);
    atomicAdd(&zout[s], er);
  }
}

// ---------------- y + key + histogram ----------------
__device__ inline unsigned fkey(float f) {
  unsigned b = __float_as_uint(f);
  return (b & 0x80000000u) ? ~b : (b | 0x80000000u);
}

__global__ void k_y(const float* wvin, const float* zin, const float* wvout,
                    const float* zout, const float* selfy, float* y, unsigned* ykey,
                    int* hist) {
  int n = blockIdx.x * blockDim.x + threadIdx.x;
  if (n < NN) {
    float v = wvin[n] / (zin[n] + 1e-6f) + wvout[n] / (zout[n] + 1e-6f) + selfy[n];
    y[n] = v;
    unsigned k = fkey(v);
    ykey[n] = k;
    atomicAdd(&hist[k >> 18], 1);
  }
}

// ---------------- histogram block sums (64 blocks) ----------------
__global__ void k_hsum(const int* __restrict__ hist, int* __restrict__ bsum) {
  __shared__ int sh[256];
  int t = threadIdx.x;
  sh[t] = hist[blockIdx.x * 256 + t];
  __syncthreads();
  for (int off = 128; off; off >>= 1) {
    if (t < off) sh[t] += sh[t + off];
    __syncthreads();
  }
  if (t == 0) bsum[blockIdx.x] = sh[0];
}

// ---------------- per-bin exclusive suffix sum (64 blocks) ----------------
__global__ void k_hfinal(const int* __restrict__ hist, const int* __restrict__ bsum,
                         int* __restrict__ suff) {
  __shared__ int sh[256];
  __shared__ int carry;
  int t = threadIdx.x;
  int bx = blockIdx.x;
  if (t < 64) {
    int m = (t > bx) ? bsum[t] : 0;
#pragma unroll
    for (int off = 32; off; off >>= 1) m += __shfl_xor(m, off);
    if (t == 0) carry = m;
  }
  int base = bx * 256;
  int own = hist[base + 255 - t];
  sh[t] = own;
  __syncthreads();
  for (int off = 1; off < 256; off <<= 1) {
    int v = (t >= off) ? sh[t - off] : 0;
    __syncthreads();
    sh[t] += v;
    __syncthreads();
  }
  suff[base + 255 - t] = carry + sh[t] - own;
}

// ---------------- scatter bin member lists ----------------
__global__ void k_scatmem(const unsigned* __restrict__ ykey, const int* __restrict__ suff,
                          int* __restrict__ cur, int* __restrict__ binlist) {
  int i = blockIdx.x * 256 + threadIdx.x;
  if (i >= NN) return;
  int b = ykey[i] >> 18;
  int slot = suff[b] + atomicAdd(&cur[b], 1);
  binlist[slot] = i;
}

// ---------------- exact rank within bin ----------------
__global__ void k_rankbin(const unsigned* __restrict__ ykey, const int* __restrict__ suff,
                          const int* __restrict__ hist, const int* __restrict__ binlist,
                          int* __restrict__ rank) {
  int i = blockIdx.x * 256 + threadIdx.x;
  if (i >= NN) return;
  unsigned ki = ykey[i];
  int b = ki >> 18;
  int base = suff[b];
  int end = base + hist[b];
  int cnt = 0;
  for (int s = base; s < end; s++) {
    int j = binlist[s];
    unsigned kj = ykey[j];
    cnt += (kj > ki || (kj == ki && j < i)) ? 1 : 0;
  }
  rank[i] = base + cnt;
}

// ---------------- selection scatter ----------------
__global__ void k_bcnt(const int* rank, int* bcnt) {
  __shared__ int sh[256];
  int i = blockIdx.x * 256 + threadIdx.x;
  int f = (i < NN && rank[i] < KK) ? 1 : 0;
  sh[threadIdx.x] = f;
  __syncthreads();
  for (int off = 128; off; off >>= 1) {
    if (threadIdx.x < off) sh[threadIdx.x] += sh[threadIdx.x + off];
    __syncthreads();
  }
  if (threadIdx.x == 0) bcnt[blockIdx.x] = sh[0];
}

__global__ void k_scan(int* bcnt, int nb) {
  __shared__ int sh[256];
  int t = threadIdx.x;
  int v = (t < nb) ? bcnt[t] : 0;
  sh[t] = v;
  __syncthreads();
  for (int off = 1; off < 256; off <<= 1) {
    int u2 = (t >= off) ? sh[t - off] : 0;
    __syncthreads();
    sh[t] += u2;
    __syncthreads();
  }
  if (t < nb) bcnt[t] = sh[t] - v;
}

__global__ void k_scatter(const int* rank, const int* bcnt, const float* y,
                          float* out_ids, int* selp, float* sig) {
  __shared__ int sh[256];
  int i = blockIdx.x * 256 + threadIdx.x;
  int f = (i < NN && rank[i] < KK) ? 1 : 0;
  sh[threadIdx.x] = f;
  __syncthreads();
  for (int off = 1; off < 256; off <<= 1) {
    int v = (threadIdx.x >= off) ? sh[threadIdx.x - off] : 0;
    __syncthreads();
    sh[threadIdx.x] += v;
    __syncthreads();
  }
  if (f) {
    int slot = bcnt[blockIdx.x] + sh[threadIdx.x] - 1;
    out_ids[slot] = (float)i;
    int p = rank[i];  // faithful quirk: sel index = rank position
    selp[slot] = p;
    sig[slot] = 1.0f / (1.0f + expf(-y[p]));
  }
}

__global__ void k_outh(const float* h, const int* selp, const float* sig, float* out) {
  long idx = (long)blockIdx.x * 256 + threadIdx.x;
  if (idx >= (long)KK * DD) return;
  int slot = (int)(idx >> 7), c = (int)(idx & 127);
  int p = selp[slot];
  out[KK + idx] = h[(size_t)p * DD + c] * sig[slot];
}

extern "C" void kernel_launch(void* const* d_in, const int* in_sizes, int n_in,
                              void* d_out, int out_size, void* d_ws, size_t ws_size,
                              hipStream_t stream) {
  const float* h = (const float*)d_in[0];
  const int* src = (const int*)d_in[1];
  const int* dst = (const int*)d_in[2];
  const int* etype = (const int*)d_in[3];
  const float* Wb = (const float*)d_in[4];
  const float* coef = (const float*)d_in[5];
  const float* wqw = (const float*)d_in[6];
  const float* wqb = (const float*)d_in[7];
  const float* wkw = (const float*)d_in[8];
  const float* wkb = (const float*)d_in[9];
  const float* wvw = (const float*)d_in[10];
  const float* wvb = (const float*)d_in[11];
  float* out = (float*)d_out;

  float* W = (float*)d_ws;
  size_t o = 0;
  f16* PKQ = (f16*)(W + o); o += (size_t)NN * 192;  // f16 [n][384]: pk0|pk1|q
  f16* Wcs = (f16*)(W + o); o += 40960;             // 81920 f16 frag-layout weights
  float* vecs = W + o; o += 512;
  float* t0 = W + o;   o += NN;
  float* t1 = W + o;   o += NN;
  float* av0 = W + o;  o += NN;
  float* av1 = W + o;  o += NN;
  float* bv0 = W + o;  o += NN;
  float* bv1 = W + o;  o += NN;
  float* u = W + o;    o += NN;
  float* selfy = W + o; o += NN;
  float* wvin = W + o;  o += NN;  // zero region start (4*NN contiguous)
  float* zin = W + o;   o += NN;
  float* wvout = W + o; o += NN;
  float* zout = W + o;  o += NN;
  float* y = W + o;     o += NN;
  unsigned* ykey = (unsigned*)(W + o); o += NN;
  float* sig = W + o;   o += KK;
  int* ibase = (int*)(W + o);
  int* rank = ibase;
  int* bcnt = ibase + NN;
  int* selp = ibase + NN + 256;
  int* hist = ibase + 2 * NN + 256;   // zero region: hist + cur contiguous
  int* cur = hist + NBIN;
  int* suff = cur + NBIN;
  int* bsum = suff + NBIN;
  int* binlist = bsum + 64;

  int nb = (NN + 255) / 256;  // 196

  k_zero<<<256, 256, 0, stream>>>(wvin, 4 * NN, hist, 2 * NBIN);
  k_smallmats2<<<(640 * 128 + 512 + 255) / 256, 256, 0, stream>>>(Wb, wqw, wkw, wvw,
                                                                  Wcs, vecs);
  k_nodeMM<<<(NN + 31) / 32, 256, 0, stream>>>(h, Wcs, wqb, wkb, vecs, coef, wvb, PKQ,
                                               t0, t1, u, av0, av1, bv0, bv1, selfy);
  k_edges16<<<NE / 16, 256, 0, stream>>>(src, dst, etype, coef, wvb, PKQ, t0, t1, u,
                                         av0, av1, bv0, bv1, wvin, zin, wvout, zout);
  k_y<<<nb, 256, 0, stream>>>(wvin, zin, wvout, zout, selfy, y, ykey, hist);
  k_hsum<<<64, 256, 0, stream>>>(hist, bsum);
  k_hfinal<<<64, 256, 0, stream>>>(hist, bsum, suff);
  k_scatmem<<<nb, 256, 0, stream>>>(ykey, suff, cur, binlist);
  k_rankbin<<<nb, 256, 0, stream>>>(ykey, suff, hist, binlist, rank);
  k_bcnt<<<nb, 256, 0, stream>>>(rank, bcnt);
  k_scan<<<1, 256, 0, stream>>>(bcnt, nb);
  k_scatter<<<nb, 256, 0, stream>>>(rank, bcnt, y, out, selp, sig);
  k_outh<<<(KK * DD) / 256, 256, 0, stream>>>(h, selp, sig, out);
}

// Round 12
// 477.791 us; speedup vs baseline: 1.9026x; 1.0352x over previous
//
#include <hip/hip_runtime.h>

#define NN 50000
#define NE 500000
#define DD 128
#define KK 25000
#define NBIN 16384
#define HP 136  // padded f16 LDS row

typedef _Float16 f16;
typedef __attribute__((ext_vector_type(8))) _Float16 f16x8;
typedef __attribute__((ext_vector_type(4))) float f32x4;

// ---------------- zero init ----------------
__global__ void k_zero(float* zf, int nf, int* zi, int ni) {
  int i = blockIdx.x * blockDim.x + threadIdx.x;
  int stride = gridDim.x * blockDim.x;
  for (int k = i; k < nf; k += stride) zf[k] = 0.0f;
  for (int k = i; k < ni; k += stride) zi[k] = 0;
}

// frag-layout store helper: Wc[k][gcol] -> Wcs
// Wcs[((ct*4+kc)*64 + lane)*8 + e] = Wc[kc*32 + (lane>>4)*8 + e][ct*16 + (lane&15)]
__device__ inline void frag_store(f16* Wcs, int gcol, int k, float val) {
  int ct = gcol >> 4, cl = gcol & 15, kc = k >> 5, kr = k & 31;
  int lane = (kr >> 3) * 16 + cl, e = kr & 7;
  Wcs[(size_t)(((ct * 4 + kc) * 64 + lane) * 8 + e)] = (f16)val;
}

// ---------------- combined weight matrix, coalesced compute ----------------
// gcol: 0-127 wqw | 128-255 Ck0 | 256-383 Ck1 | 384-511 Dk0 | 512-639 Dk1
__global__ void k_smallmats3(const float* __restrict__ Wb, const float* __restrict__ wqw,
                             const float* __restrict__ wkw, const float* __restrict__ wvw,
                             f16* __restrict__ Wcs, float* __restrict__ vecs) {
  int b = blockIdx.x, tid = threadIdx.x;
  if (b < 256) {
    // Ck0/Ck1/Dk0/Dk1: 2 rows per block, 1 element per thread
    int mat = b >> 6;            // 0:Ck0 1:Ck1 2:Dk0 3:Dk1
    int i = (b & 63) * 2 + (tid >> 7);   // k-row 0..127
    int c = tid & 127;
    int basis = mat & 1;
    int rowoff = (mat >> 1) * DD;
    const float* wrow = Wb + (size_t)(basis * 2 * DD + rowoff + i) * DD;
    float s = 0.f;
    for (int m = 0; m < DD; m++) s += wrow[m] * wkw[m * DD + c];
    frag_store(Wcs, 128 + mat * 128 + c, i, s);
  } else if (b < 260) {
    int which = b - 256;
    if (tid < DD) {
      int basis = which & 1, rowoff = (which >> 1) * DD;
      const float* wrow = Wb + (size_t)(basis * 2 * DD + rowoff + tid) * DD;
      float s = 0.f;
      for (int m = 0; m < DD; m++) s += wrow[m] * wvw[m];
      vecs[which * DD + tid] = s;
    }
  } else {
    // wqw copy into frag layout
    for (int e = 0; e < 64; e++) {
      int idx = e * 256 + tid;   // 0..16383
      int k = idx >> 7, gcol = idx & 127;
      frag_store(Wcs, gcol, k, wqw[k * DD + gcol]);
    }
  }
}

// ---------------- MFMA node pass: 32 nodes/block, 4 waves ----------------
// outputs: PKQ[n][384] f16 = {pk0[128] | pk1[128] | q[128]}, t0,t1,u,av*,bv*,selfy
__global__ void __launch_bounds__(256) k_nodeMM(
    const float* __restrict__ h, const f16* __restrict__ Wcs,
    const float* __restrict__ wqb, const float* __restrict__ wkb,
    const float* __restrict__ vecs, const float* __restrict__ coef,
    const float* __restrict__ wvb, f16* __restrict__ pkq, float* __restrict__ t0o,
    float* __restrict__ t1o, float* __restrict__ uo, float* __restrict__ av0o,
    float* __restrict__ av1o, float* __restrict__ bv0o, float* __restrict__ bv1o,
    float* __restrict__ selfyo) {
  __shared__ f16 hsF[32 * HP];
  __shared__ f16 pkqL[32 * 384];
  int tid = threadIdx.x;
  int n0 = blockIdx.x * 32;
  for (int idx = tid; idx < 32 * DD; idx += 256) {
    int r = idx >> 7, c = idx & 127;
    int n = n0 + r;
    float v = (n < NN) ? h[(size_t)n * DD + c] : 0.f;
    hsF[r * HP + c] = (f16)v;
  }
  __syncthreads();
  int lane = tid & 63, wid = tid >> 6;
  int nh = wid & 1;            // node half
  int ctb = (wid >> 1) * 20;   // col-tile base
  int cl = lane & 15, kq = lane >> 4;
  int base_node = 16 * nh;

  f16x8 afr[4];
#pragma unroll
  for (int kc = 0; kc < 4; kc++)
    afr[kc] = *(const f16x8*)&hsF[(base_node + cl) * HP + kc * 32 + kq * 8];

  f32x4 acc[20];
#pragma unroll
  for (int t = 0; t < 20; t++) acc[t] = (f32x4){0.f, 0.f, 0.f, 0.f};

  const f16x8* Wf = (const f16x8*)Wcs;
#pragma unroll
  for (int t = 0; t < 20; t++) {
    int ct = ctb + t;
#pragma unroll
    for (int kc = 0; kc < 4; kc++) {
      f16x8 bfr = Wf[(ct * 4 + kc) * 64 + lane];
      acc[t] = __builtin_amdgcn_mfma_f32_16x16x32_f16(afr[kc], bfr, acc[t], 0, 0, 0);
    }
  }

  // ---- pass 1: stage q / pk0 / pk1 into pkqL (LDS), u partials ----
  float upart[4] = {0.f, 0.f, 0.f, 0.f};
#pragma unroll
  for (int t = 0; t < 20; t++) {
    int ct = ctb + t;
    int gc = ct * 16 + cl;
    if (ct < 8) {
      float wq = wqb[gc], wk = wkb[gc];
#pragma unroll
      for (int r = 0; r < 4; r++) {
        int row = base_node + kq * 4 + r;
        float qv = acc[t][r] + wq;
        pkqL[row * 384 + 256 + gc] = (f16)qv;
        upart[r] += wk * qv;
      }
    } else if (ct < 16) {
#pragma unroll
      for (int r = 0; r < 4; r++)
        pkqL[(base_node + kq * 4 + r) * 384 + (gc - 128)] = (f16)acc[t][r];
    } else if (ct < 24) {
#pragma unroll
      for (int r = 0; r < 4; r++)
        pkqL[(base_node + kq * 4 + r) * 384 + 128 + (gc - 256)] = (f16)acc[t][r];
    }
  }
  if (ctb == 0) {
#pragma unroll
    for (int r = 0; r < 4; r++) {
#pragma unroll
      for (int off = 1; off < 16; off <<= 1) upart[r] += __shfl_xor(upart[r], off);
      int n = n0 + base_node + kq * 4 + r;
      if (cl == 0 && n < NN) uo[n] = upart[r];
    }
  }
  __syncthreads();
  // ---- pass 2: t_b = d_b . q (d-waves, q from pkqL f16) ----
  if (ctb == 20) {
    float tp0[4] = {0.f, 0.f, 0.f, 0.f}, tp1[4] = {0.f, 0.f, 0.f, 0.f};
#pragma unroll
    for (int t = 0; t < 20; t++) {
      int ct = ctb + t;
      int gc = ct * 16 + cl;
      if (ct >= 24 && ct < 32) {
#pragma unroll
        for (int r = 0; r < 4; r++)
          tp0[r] += acc[t][r] *
                    (float)pkqL[(base_node + kq * 4 + r) * 384 + 256 + (gc - 384)];
      } else if (ct >= 32) {
#pragma unroll
        for (int r = 0; r < 4; r++)
          tp1[r] += acc[t][r] *
                    (float)pkqL[(base_node + kq * 4 + r) * 384 + 256 + (gc - 512)];
      }
    }
#pragma unroll
    for (int r = 0; r < 4; r++) {
#pragma unroll
      for (int off = 1; off < 16; off <<= 1) {
        tp0[r] += __shfl_xor(tp0[r], off);
        tp1[r] += __shfl_xor(tp1[r], off);
      }
      int n = n0 + base_node + kq * 4 + r;
      if (cl == 0 && n < NN) { t0o[n] = tp0[r]; t1o[n] = tp1[r]; }
    }
  }
  // ---- pass 3: coalesced copy pkqL -> global PKQ ----
  // 32 rows * 48 f16x8 = 1536 vectors, 6 iterations
#pragma unroll
  for (int it = 0; it < 6; it++) {
    int idx = it * 256 + tid;
    int row = idx / 48, sub = idx - row * 48;
    int n = n0 + row;
    if (n < NN)
      *(f16x8*)&pkq[(size_t)n * 384 + sub * 8] =
          *(const f16x8*)&pkqL[row * 384 + sub * 8];
  }
  // ---- av/bv/selfy from staged h ----
  int nn2 = tid >> 3, sub = tid & 7;
  float a0 = 0.f, a1 = 0.f, b0 = 0.f, b1 = 0.f;
  for (int c = sub * 16; c < sub * 16 + 16; c++) {
    float hv = (float)hsF[nn2 * HP + c];
    a0 += hv * vecs[c];
    a1 += hv * vecs[DD + c];
    b0 += hv * vecs[2 * DD + c];
    b1 += hv * vecs[3 * DD + c];
  }
#pragma unroll
  for (int off = 1; off < 8; off <<= 1) {
    a0 += __shfl_xor(a0, off);
    a1 += __shfl_xor(a1, off);
    b0 += __shfl_xor(b0, off);
    b1 += __shfl_xor(b1, off);
  }
  if (sub == 0) {
    int n = n0 + nn2;
    if (n < NN) {
      av0o[n] = a0; av1o[n] = a1; bv0o[n] = b0; bv1o[n] = b1;
      float c40 = coef[4 * 2 + 0], c41 = coef[4 * 2 + 1];
      selfyo[n] = c40 * (a0 + b0) + c41 * (a1 + b1) + wvb[0];
    }
  }
}

// ---------------- edge kernel: 16 lanes per edge, f16 rows ----------------
__global__ void __launch_bounds__(256) k_edges16(
    const int* __restrict__ src, const int* __restrict__ dst,
    const int* __restrict__ et, const float* __restrict__ coef,
    const float* __restrict__ wvb, const f16* __restrict__ pkq,
    const float* __restrict__ t0, const float* __restrict__ t1,
    const float* __restrict__ u, const float* __restrict__ av0,
    const float* __restrict__ av1, const float* __restrict__ bv0,
    const float* __restrict__ bv1, float* wvin, float* zin, float* wvout,
    float* zout) {
  int tid = threadIdx.x;
  int sub = tid & 15;
  int g = tid >> 4;
  long e = (long)blockIdx.x * 16 + g;
  int s = src[e], d = dst[e], t = et[e];
  float c0 = coef[t * 2], c1 = coef[t * 2 + 1];
  const f16* rs = pkq + (size_t)s * 384;
  const f16* rd = pkq + (size_t)d * 384;
  f16x8 p0s = *(const f16x8*)(rs + sub * 8);
  f16x8 p1s = *(const f16x8*)(rs + 128 + sub * 8);
  f16x8 qse = *(const f16x8*)(rs + 256 + sub * 8);
  f16x8 p0d = *(const f16x8*)(rd + sub * 8);
  f16x8 p1d = *(const f16x8*)(rd + 128 + sub * 8);
  f16x8 qde = *(const f16x8*)(rd + 256 + sub * 8);
  float df = 0.f, dr = 0.f;
#pragma unroll
  for (int j = 0; j < 8; j++) {
    df += (c0 * (float)p0s[j] + c1 * (float)p1s[j]) * (float)qde[j];
    dr += (c0 * (float)p0d[j] + c1 * (float)p1d[j]) * (float)qse[j];
  }
#pragma unroll
  for (int off = 8; off; off >>= 1) {
    df += __shfl_xor(df, off);
    dr += __shfl_xor(dr, off);
  }
  if (sub == 0) {
    const float scale = 11.3137084989847604f;  // sqrt(128)
    float wvbd = wvb[0];
    float sf = (df + c0 * t0[d] + c1 * t1[d] + u[d]) / scale;
    sf = fminf(fmaxf(sf, -10.0f), 10.0f);
    float ef = expf(sf);
    float nvf = c0 * (av0[s] + bv0[d]) + c1 * (av1[s] + bv1[d]) + wvbd;
    atomicAdd(&wvin[d], ef * nvf);
    atomicAdd(&zin[d], ef);
    float sr = (dr + c0 * t0[s] + c1 * t1[s] + u[s]) / scale;
    sr = fminf(fmaxf(sr, -10.0f), 10.0f);
    float er = expf(sr);
    float nvr = c0 * (av0[d] + bv0[s]) + c1 * (av1[d] + bv1[s]) + wvbd;
    atomicAdd(&wvout[s], er * nvr);
    atomicAdd(&zout[s], er);
  }
}

// ---------------- y + key + histogram ----------------
__device__ inline unsigned fkey(float f) {
  unsigned b = __float_as_uint(f);
  return (b & 0x80000000u) ? ~b : (b | 0x80000000u);
}

__global__ void k_y(const float* wvin, const float* zin, const float* wvout,
                    const float* zout, const float* selfy, float* y, unsigned* ykey,
                    int* hist) {
  int n = blockIdx.x * blockDim.x + threadIdx.x;
  if (n < NN) {
    float v = wvin[n] / (zin[n] + 1e-6f) + wvout[n] / (zout[n] + 1e-6f) + selfy[n];
    y[n] = v;
    unsigned k = fkey(v);
    ykey[n] = k;
    atomicAdd(&hist[k >> 18], 1);
  }
}

// ---------------- histogram block sums (64 blocks) ----------------
__global__ void k_hsum(const int* __restrict__ hist, int* __restrict__ bsum) {
  __shared__ int sh[256];
  int t = threadIdx.x;
  sh[t] = hist[blockIdx.x * 256 + t];
  __syncthreads();
  for (int off = 128; off; off >>= 1) {
    if (t < off) sh[t] += sh[t + off];
    __syncthreads();
  }
  if (t == 0) bsum[blockIdx.x] = sh[0];
}

// ---------------- per-bin exclusive suffix sum (64 blocks) ----------------
__global__ void k_hfinal(const int* __restrict__ hist, const int* __restrict__ bsum,
                         int* __restrict__ suff) {
  __shared__ int sh[256];
  __shared__ int carry;
  int t = threadIdx.x;
  int bx = blockIdx.x;
  if (t < 64) {
    int m = (t > bx) ? bsum[t] : 0;
#pragma unroll
    for (int off = 32; off; off >>= 1) m += __shfl_xor(m, off);
    if (t == 0) carry = m;
  }
  int base = bx * 256;
  int own = hist[base + 255 - t];
  sh[t] = own;
  __syncthreads();
  for (int off = 1; off < 256; off <<= 1) {
    int v = (t >= off) ? sh[t - off] : 0;
    __syncthreads();
    sh[t] += v;
    __syncthreads();
  }
  suff[base + 255 - t] = carry + sh[t] - own;
}

// ---------------- scatter bin member lists ----------------
__global__ void k_scatmem(const unsigned* __restrict__ ykey, const int* __restrict__ suff,
                          int* __restrict__ cur, int* __restrict__ binlist) {
  int i = blockIdx.x * 256 + threadIdx.x;
  if (i >= NN) return;
  int b = ykey[i] >> 18;
  int slot = suff[b] + atomicAdd(&cur[b], 1);
  binlist[slot] = i;
}

// ---------------- exact rank within bin (+ fused block count) ----------------
__global__ void k_rankbin(const unsigned* __restrict__ ykey, const int* __restrict__ suff,
                          const int* __restrict__ hist, const int* __restrict__ binlist,
                          int* __restrict__ rank, int* __restrict__ bcnt) {
  __shared__ int sh[256];
  int i = blockIdx.x * 256 + threadIdx.x;
  int rk = NN;
  if (i < NN) {
    unsigned ki = ykey[i];
    int b = ki >> 18;
    int base = suff[b];
    int end = base + hist[b];
    int cnt = 0;
    for (int s = base; s < end; s++) {
      int j = binlist[s];
      unsigned kj = ykey[j];
      cnt += (kj > ki || (kj == ki && j < i)) ? 1 : 0;
    }
    rk = base + cnt;
    rank[i] = rk;
  }
  sh[threadIdx.x] = (rk < KK) ? 1 : 0;
  __syncthreads();
  for (int off = 128; off; off >>= 1) {
    if (threadIdx.x < off) sh[threadIdx.x] += sh[threadIdx.x + off];
    __syncthreads();
  }
  if (threadIdx.x == 0) bcnt[blockIdx.x] = sh[0];
}

__global__ void k_scan(int* bcnt, int nb) {
  __shared__ int sh[256];
  int t = threadIdx.x;
  int v = (t < nb) ? bcnt[t] : 0;
  sh[t] = v;
  __syncthreads();
  for (int off = 1; off < 256; off <<= 1) {
    int u2 = (t >= off) ? sh[t - off] : 0;
    __syncthreads();
    sh[t] += u2;
    __syncthreads();
  }
  if (t < nb) bcnt[t] = sh[t] - v;
}

__global__ void k_scatter(const int* rank, const int* bcnt, const float* y,
                          float* out_ids, int* selp, float* sig) {
  __shared__ int sh[256];
  int i = blockIdx.x * 256 + threadIdx.x;
  int f = (i < NN && rank[i] < KK) ? 1 : 0;
  sh[threadIdx.x] = f;
  __syncthreads();
  for (int off = 1; off < 256; off <<= 1) {
    int v = (threadIdx.x >= off) ? sh[threadIdx.x - off] : 0;
    __syncthreads();
    sh[threadIdx.x] += v;
    __syncthreads();
  }
  if (f) {
    int slot = bcnt[blockIdx.x] + sh[threadIdx.x] - 1;
    out_ids[slot] = (float)i;
    int p = rank[i];  // faithful quirk: sel index = rank position
    selp[slot] = p;
    sig[slot] = 1.0f / (1.0f + expf(-y[p]));
  }
}

__global__ void k_outh(const float* h, const int* selp, const float* sig, float* out) {
  long idx = (long)blockIdx.x * 256 + threadIdx.x;
  if (idx >= (long)KK * DD) return;
  int slot = (int)(idx >> 7), c = (int)(idx & 127);
  int p = selp[slot];
  out[KK + idx] = h[(size_t)p * DD + c] * sig[slot];
}

extern "C" void kernel_launch(void* const* d_in, const int* in_sizes, int n_in,
                              void* d_out, int out_size, void* d_ws, size_t ws_size,
                              hipStream_t stream) {
  const float* h = (const float*)d_in[0];
  const int* src = (const int*)d_in[1];
  const int* dst = (const int*)d_in[2];
  const int* etype = (const int*)d_in[3];
  const float* Wb = (const float*)d_in[4];
  const float* coef = (const float*)d_in[5];
  const float* wqw = (const float*)d_in[6];
  const float* wqb = (const float*)d_in[7];
  const float* wkw = (const float*)d_in[8];
  const float* wkb = (const float*)d_in[9];
  const float* wvw = (const float*)d_in[10];
  const float* wvb = (const float*)d_in[11];
  float* out = (float*)d_out;

  float* W = (float*)d_ws;
  size_t o = 0;
  f16* PKQ = (f16*)(W + o); o += (size_t)NN * 192;  // f16 [n][384]: pk0|pk1|q
  f16* Wcs = (f16*)(W + o); o += 40960;             // 81920 f16 frag-layout weights
  float* vecs = W + o; o += 512;
  float* t0 = W + o;   o += NN;
  float* t1 = W + o;   o += NN;
  float* av0 = W + o;  o += NN;
  float* av1 = W + o;  o += NN;
  float* bv0 = W + o;  o += NN;
  float* bv1 = W + o;  o += NN;
  float* u = W + o;    o += NN;
  float* selfy = W + o; o += NN;
  float* wvin = W + o;  o += NN;  // zero region start (4*NN contiguous)
  float* zin = W + o;   o += NN;
  float* wvout = W + o; o += NN;
  float* zout = W + o;  o += NN;
  float* y = W + o;     o += NN;
  unsigned* ykey = (unsigned*)(W + o); o += NN;
  float* sig = W + o;   o += KK;
  int* ibase = (int*)(W + o);
  int* rank = ibase;
  int* bcnt = ibase + NN;
  int* selp = ibase + NN + 256;
  int* hist = ibase + 2 * NN + 256;   // zero region: hist + cur contiguous
  int* cur = hist + NBIN;
  int* suff = cur + NBIN;
  int* bsum = suff + NBIN;
  int* binlist = bsum + 64;

  int nb = (NN + 255) / 256;  // 196

  k_zero<<<256, 256, 0, stream>>>(wvin, 4 * NN, hist, 2 * NBIN);
  k_smallmats3<<<261, 256, 0, stream>>>(Wb, wqw, wkw, wvw, Wcs, vecs);
  k_nodeMM<<<(NN + 31) / 32, 256, 0, stream>>>(h, Wcs, wqb, wkb, vecs, coef, wvb, PKQ,
                                               t0, t1, u, av0, av1, bv0, bv1, selfy);
  k_edges16<<<NE / 16, 256, 0, stream>>>(src, dst, etype, coef, wvb, PKQ, t0, t1, u,
                                         av0, av1, bv0, bv1, wvin, zin, wvout, zout);
  k_y<<<nb, 256, 0, stream>>>(wvin, zin, wvout, zout, selfy, y, ykey, hist);
  k_hsum<<<64, 256, 0, stream>>>(hist, bsum);
  k_hfinal<<<64, 256, 0, stream>>>(hist, bsum, suff);
  k_scatmem<<<nb, 256, 0, stream>>>(ykey, suff, cur, binlist);
  k_rankbin<<<nb, 256, 0, stream>>>(ykey, suff, hist, binlist, rank, bcnt);
  k_scan<<<1, 256, 0, stream>>>(bcnt, nb);
  k_scatter<<<nb, 256, 0, stream>>>(rank, bcnt, y, out, selp, sig);
  k_outh<<<(KK * DD) / 256, 256, 0, stream>>>(h, selp, sig, out);
}